// Round 1
// baseline (1464.917 us; speedup 1.0000x reference)
//
#include <hip/hip_runtime.h>

#define N_NODES 100000
#define N_EDGES 1600000
#define D 64
#define NUM_GRAPHS 64
#define EPS 1e-5f

// ---------------------------------------------------------------------------
// Kernel A: agg[dst] += edge_attr * x[src]   (atomic scatter, 16 thr/edge)
// ---------------------------------------------------------------------------
__global__ __launch_bounds__(256) void scatter_kernel(
    const float* __restrict__ x,
    const int* __restrict__ src_idx,
    const int* __restrict__ dst_idx,
    const float* __restrict__ ea,
    float* __restrict__ agg)
{
    long long gid = (long long)blockIdx.x * blockDim.x + threadIdx.x;
    if (gid >= (long long)N_EDGES * 16) return;
    int e = (int)(gid >> 4);
    int q = (int)(gid & 15);
    int s = src_idx[e];
    int d = dst_idx[e];
    float w = ea[e];
    float4 v = reinterpret_cast<const float4*>(x)[(size_t)s * 16 + q];
    float* out = agg + (size_t)d * 64 + q * 4;
    atomicAdd(out + 0, w * v.x);
    atomicAdd(out + 1, w * v.y);
    atomicAdd(out + 2, w * v.z);
    atomicAdd(out + 3, w * v.w);
}

// ---------------------------------------------------------------------------
// Kernel B: h = relu(agg @ W_rel^T + b_rel + x @ W_root^T), in-place over agg
// One node per thread; W (transposed) in LDS, broadcast reads.
// ---------------------------------------------------------------------------
#define BLOCK_B 128
__global__ __launch_bounds__(BLOCK_B) void dense_kernel(
    float* __restrict__ aggh,          // in: agg, out: h (same buffer)
    const float* __restrict__ x,
    const float* __restrict__ W_rel,
    const float* __restrict__ b_rel,
    const float* __restrict__ W_root)
{
    __shared__ float Wl[128 * 64];     // Wl[k][d]; k<64: W_rel, k>=64: W_root
    __shared__ float bl[64];
    int tid = threadIdx.x;
    for (int i = tid; i < 64 * 64; i += BLOCK_B) {
        int k = i >> 6, d = i & 63;
        Wl[i]        = W_rel[d * 64 + k];
        Wl[4096 + i] = W_root[d * 64 + k];
    }
    if (tid < 64) bl[tid] = b_rel[tid];
    __syncthreads();

    int node = blockIdx.x * BLOCK_B + tid;
    if (node >= N_NODES) return;

    float acc[64];
    #pragma unroll
    for (int d = 0; d < 64; ++d) acc[d] = bl[d];

    float* myrow = aggh + (size_t)node * 64;
    const float4* av = reinterpret_cast<const float4*>(myrow);
    const float4* xv = reinterpret_cast<const float4*>(x + (size_t)node * 64);

    #pragma unroll 1
    for (int half = 0; half < 2; ++half) {
        const float4* src = half ? xv : av;
        const float* Wbase = Wl + half * 4096;
        #pragma unroll 1
        for (int kc = 0; kc < 8; ++kc) {
            float4 v0 = src[kc * 2];
            float4 v1 = src[kc * 2 + 1];
            float vv[8] = {v0.x, v0.y, v0.z, v0.w, v1.x, v1.y, v1.z, v1.w};
            #pragma unroll
            for (int j = 0; j < 8; ++j) {
                const float* wrow = Wbase + (kc * 8 + j) * 64;
                #pragma unroll
                for (int d = 0; d < 64; ++d)
                    acc[d] = fmaf(vv[j], wrow[d], acc[d]);
            }
        }
    }

    float4* hv = reinterpret_cast<float4*>(myrow);
    #pragma unroll
    for (int d4 = 0; d4 < 16; ++d4) {
        float4 o;
        o.x = fmaxf(acc[d4 * 4 + 0], 0.f);
        o.y = fmaxf(acc[d4 * 4 + 1], 0.f);
        o.z = fmaxf(acc[d4 * 4 + 2], 0.f);
        o.w = fmaxf(acc[d4 * 4 + 3], 0.f);
        hv[d4] = o;
    }
}

// ---------------------------------------------------------------------------
// Kernel C1: per-(graph, dim) sum(h) and sum(h^2), plus per-graph count.
// lane = dim; each wave walks NPW consecutive nodes (batch_index is sorted),
// flushing with atomics at segment boundaries.
// ---------------------------------------------------------------------------
#define NPW 32
__global__ __launch_bounds__(256) void stats_kernel(
    const float* __restrict__ h,
    const int* __restrict__ batch,
    float* __restrict__ gsum,
    float* __restrict__ gsum2,
    float* __restrict__ gcnt)
{
    int wave = (int)((blockIdx.x * blockDim.x + threadIdx.x) >> 6);
    int lane = threadIdx.x & 63;
    int base = wave * NPW;
    if (base >= N_NODES) return;
    int end = min(base + NPW, N_NODES);

    int gcur = batch[base];
    float s = 0.f, s2 = 0.f, cnt = 0.f;
    for (int n = base; n < end; ++n) {
        int g = batch[n];
        if (g != gcur) {
            atomicAdd(&gsum[gcur * 64 + lane], s);
            atomicAdd(&gsum2[gcur * 64 + lane], s2);
            if (lane == 0) atomicAdd(&gcnt[gcur], cnt);
            s = 0.f; s2 = 0.f; cnt = 0.f;
            gcur = g;
        }
        float v = h[(size_t)n * 64 + lane];
        s += v;
        s2 = fmaf(v, v, s2);
        cnt += 1.f;
    }
    atomicAdd(&gsum[gcur * 64 + lane], s);
    atomicAdd(&gsum2[gcur * 64 + lane], s2);
    if (lane == 0) atomicAdd(&gcnt[gcur], cnt);
}

// ---------------------------------------------------------------------------
// Kernel C2: fold stats into per-(g,d) affine A,B:  out = A*h + B
// ---------------------------------------------------------------------------
__global__ __launch_bounds__(256) void finalize_kernel(
    const float* __restrict__ gsum,
    const float* __restrict__ gsum2,
    const float* __restrict__ gcnt,
    const float* __restrict__ gn_w,
    const float* __restrict__ gn_b,
    const float* __restrict__ gn_ms,
    float* __restrict__ Ag,
    float* __restrict__ Bg)
{
    int i = blockIdx.x * blockDim.x + threadIdx.x;
    if (i >= NUM_GRAPHS * 64) return;
    int g = i >> 6, d = i & 63;
    float c = fmaxf(gcnt[g], 1.f);
    float m = gsum[i] / c;
    float q = gsum2[i] / c;
    float s = gn_ms[d];
    // var = E[(h - s*m)^2] = E[h^2] - (2s - s^2) m^2
    float var = q - (2.f * s - s * s) * m * m;
    float inv = rsqrtf(fmaxf(var, 0.f) + EPS);
    float A = gn_w[d] * inv;
    Ag[i] = A;
    Bg[i] = gn_b[d] - A * s * m;
}

// ---------------------------------------------------------------------------
// Kernel C3: out[n][d] = A[g][d] * h[n][d] + B[g][d]
// ---------------------------------------------------------------------------
__global__ __launch_bounds__(256) void apply_kernel(
    const float* __restrict__ h,
    const int* __restrict__ batch,
    const float* __restrict__ Ag,
    const float* __restrict__ Bg,
    float* __restrict__ out)
{
    long long gid = (long long)blockIdx.x * blockDim.x + threadIdx.x;
    if (gid >= (long long)N_NODES * 16) return;
    int n = (int)(gid >> 4);
    int q = (int)(gid & 15);
    int g = batch[n];
    float4 hv = reinterpret_cast<const float4*>(h)[gid];
    float4 A = reinterpret_cast<const float4*>(Ag)[g * 16 + q];
    float4 B = reinterpret_cast<const float4*>(Bg)[g * 16 + q];
    float4 o;
    o.x = fmaf(A.x, hv.x, B.x);
    o.y = fmaf(A.y, hv.y, B.y);
    o.z = fmaf(A.z, hv.z, B.z);
    o.w = fmaf(A.w, hv.w, B.w);
    reinterpret_cast<float4*>(out)[gid] = o;
}

// ---------------------------------------------------------------------------
extern "C" void kernel_launch(void* const* d_in, const int* in_sizes, int n_in,
                              void* d_out, int out_size, void* d_ws, size_t ws_size,
                              hipStream_t stream)
{
    const float* x      = (const float*)d_in[0];
    const int*   ei     = (const int*)d_in[1];     // [2][E]
    const float* ea     = (const float*)d_in[2];
    const int*   batch  = (const int*)d_in[3];
    const float* W_rel  = (const float*)d_in[4];
    const float* b_rel  = (const float*)d_in[5];
    const float* W_root = (const float*)d_in[6];
    const float* gn_w   = (const float*)d_in[7];
    const float* gn_b   = (const float*)d_in[8];
    const float* gn_ms  = (const float*)d_in[9];

    float* agg   = (float*)d_ws;                           // N*64 (agg, then h)
    float* gsum  = agg + (size_t)N_NODES * 64;             // G*64
    float* gsum2 = gsum + NUM_GRAPHS * 64;                 // G*64
    float* gcnt  = gsum2 + NUM_GRAPHS * 64;                // 64
    float* Ag    = gcnt + 64;                              // G*64
    float* Bg    = Ag + NUM_GRAPHS * 64;                   // G*64

    size_t zero_bytes = ((size_t)N_NODES * 64 + 2 * NUM_GRAPHS * 64 + 64) * sizeof(float);
    hipMemsetAsync(d_ws, 0, zero_bytes, stream);

    // A: scatter
    {
        long long total = (long long)N_EDGES * 16;
        int blocks = (int)((total + 255) / 256);
        scatter_kernel<<<blocks, 256, 0, stream>>>(x, ei, ei + N_EDGES, ea, agg);
    }
    // B: dense + relu (in-place agg -> h)
    {
        int blocks = (N_NODES + BLOCK_B - 1) / BLOCK_B;
        dense_kernel<<<blocks, BLOCK_B, 0, stream>>>(agg, x, W_rel, b_rel, W_root);
    }
    // C1: stats
    {
        int waves = (N_NODES + NPW - 1) / NPW;
        int blocks = (waves + 3) / 4;
        stats_kernel<<<blocks, 256, 0, stream>>>(agg, batch, gsum, gsum2, gcnt);
    }
    // C2: finalize
    finalize_kernel<<<(NUM_GRAPHS * 64 + 255) / 256, 256, 0, stream>>>(
        gsum, gsum2, gcnt, gn_w, gn_b, gn_ms, Ag, Bg);
    // C3: apply
    {
        long long total = (long long)N_NODES * 16;
        int blocks = (int)((total + 255) / 256);
        apply_kernel<<<blocks, 256, 0, stream>>>(agg, batch, Ag, Bg, (float*)d_out);
    }
}

// Round 2
// 373.458 us; speedup vs baseline: 3.9226x; 3.9226x over previous
//
#include <hip/hip_runtime.h>

#define N_NODES 100000
#define N_EDGES 1600000
#define D 64
#define NUM_GRAPHS 64
#define EPS 1e-5f

#define SCAN_T 256
#define SCAN_E 8
#define SCAN_CHUNK (SCAN_T * SCAN_E)            // 2048
#define NSCAN ((N_NODES + SCAN_CHUNK - 1) / SCAN_CHUNK)   // 49

// ---------------------------------------------------------------------------
// CSR path kernel 1: degree histogram of dst
// ---------------------------------------------------------------------------
__global__ __launch_bounds__(256) void hist_kernel(
    const int* __restrict__ dst_idx, int* __restrict__ deg)
{
    int e = blockIdx.x * blockDim.x + threadIdx.x;
    if (e >= N_EDGES) return;
    atomicAdd(&deg[dst_idx[e]], 1);
}

// ---------------------------------------------------------------------------
// CSR path kernel 2a: per-chunk exclusive scan (2048 elems/block)
// ---------------------------------------------------------------------------
__global__ __launch_bounds__(SCAN_T) void scan1_kernel(
    const int* __restrict__ deg, int* __restrict__ offsets,
    int* __restrict__ blocksum)
{
    __shared__ int lds[SCAN_T];
    int b = blockIdx.x, t = threadIdx.x;
    int base = b * SCAN_CHUNK + t * SCAN_E;
    int v[SCAN_E];
    int s = 0;
    #pragma unroll
    for (int i = 0; i < SCAN_E; ++i) {
        v[i] = (base + i < N_NODES) ? deg[base + i] : 0;
        s += v[i];
    }
    lds[t] = s;
    __syncthreads();
    for (int off = 1; off < SCAN_T; off <<= 1) {
        int val = lds[t];
        int add = (t >= off) ? lds[t - off] : 0;
        __syncthreads();
        lds[t] = val + add;
        __syncthreads();
    }
    if (t == SCAN_T - 1) blocksum[b] = lds[SCAN_T - 1];
    int run = (t == 0) ? 0 : lds[t - 1];
    #pragma unroll
    for (int i = 0; i < SCAN_E; ++i) {
        if (base + i < N_NODES) offsets[base + i] = run;
        run += v[i];
    }
}

// ---------------------------------------------------------------------------
// CSR path kernel 2b: scan the 49 block sums (single wave)
// ---------------------------------------------------------------------------
__global__ __launch_bounds__(64) void scan2_kernel(
    const int* __restrict__ blocksum, int* __restrict__ blockoff)
{
    __shared__ int lds[64];
    int t = threadIdx.x;
    lds[t] = (t < NSCAN) ? blocksum[t] : 0;
    __syncthreads();
    for (int off = 1; off < 64; off <<= 1) {
        int val = lds[t];
        int add = (t >= off) ? lds[t - off] : 0;
        __syncthreads();
        lds[t] = val + add;
        __syncthreads();
    }
    if (t < NSCAN) blockoff[t] = (t == 0) ? 0 : lds[t - 1];
}

// ---------------------------------------------------------------------------
// CSR path kernel 2c: add block offsets; init cursor; set offsets[N]
// ---------------------------------------------------------------------------
__global__ __launch_bounds__(256) void scan3_kernel(
    int* __restrict__ offsets, const int* __restrict__ blockoff,
    int* __restrict__ cursor)
{
    int i = blockIdx.x * blockDim.x + threadIdx.x;
    if (i < N_NODES) {
        int v = offsets[i] + blockoff[i / SCAN_CHUNK];
        offsets[i] = v;
        cursor[i] = v;
    }
    if (i == 0) offsets[N_NODES] = N_EDGES;
}

// ---------------------------------------------------------------------------
// CSR path kernel 3: fill CSR with packed {src, weight_bits}
// ---------------------------------------------------------------------------
__global__ __launch_bounds__(256) void fill_kernel(
    const int* __restrict__ src_idx, const int* __restrict__ dst_idx,
    const float* __restrict__ ea, int* __restrict__ cursor,
    int2* __restrict__ csr)
{
    int e = blockIdx.x * blockDim.x + threadIdx.x;
    if (e >= N_EDGES) return;
    int s = src_idx[e];
    int d = dst_idx[e];
    float w = ea[e];
    int pos = atomicAdd(&cursor[d], 1);
    csr[pos] = make_int2(s, __float_as_int(w));
}

// ---------------------------------------------------------------------------
// CSR path kernel 4: gather-aggregate. One wave per node, lane = dim.
// ---------------------------------------------------------------------------
__global__ __launch_bounds__(256) void gather_kernel(
    const float* __restrict__ x, const int* __restrict__ offsets,
    const int2* __restrict__ csr, float* __restrict__ agg)
{
    int wid = (int)((blockIdx.x * blockDim.x + threadIdx.x) >> 6);
    if (wid >= N_NODES) return;
    int lane = threadIdx.x & 63;
    int beg = __builtin_amdgcn_readfirstlane(offsets[wid]);
    int end = __builtin_amdgcn_readfirstlane(offsets[wid + 1]);
    float acc0 = 0.f, acc1 = 0.f;
    int j = beg;
    for (; j + 1 < end; j += 2) {
        int2 a = csr[j];
        int2 b = csr[j + 1];
        acc0 = fmaf(__int_as_float(a.y), x[(size_t)a.x * 64 + lane], acc0);
        acc1 = fmaf(__int_as_float(b.y), x[(size_t)b.x * 64 + lane], acc1);
    }
    if (j < end) {
        int2 a = csr[j];
        acc0 = fmaf(__int_as_float(a.y), x[(size_t)a.x * 64 + lane], acc0);
    }
    agg[(size_t)wid * 64 + lane] = acc0 + acc1;
}

// ---------------------------------------------------------------------------
// Fallback kernel: atomic scatter (used only if ws too small)
// ---------------------------------------------------------------------------
__global__ __launch_bounds__(256) void scatter_kernel(
    const float* __restrict__ x,
    const int* __restrict__ src_idx,
    const int* __restrict__ dst_idx,
    const float* __restrict__ ea,
    float* __restrict__ agg)
{
    long long gid = (long long)blockIdx.x * blockDim.x + threadIdx.x;
    if (gid >= (long long)N_EDGES * 16) return;
    int e = (int)(gid >> 4);
    int q = (int)(gid & 15);
    int s = src_idx[e];
    int d = dst_idx[e];
    float w = ea[e];
    float4 v = reinterpret_cast<const float4*>(x)[(size_t)s * 16 + q];
    float* out = agg + (size_t)d * 64 + q * 4;
    atomicAdd(out + 0, w * v.x);
    atomicAdd(out + 1, w * v.y);
    atomicAdd(out + 2, w * v.z);
    atomicAdd(out + 3, w * v.w);
}

// ---------------------------------------------------------------------------
// Kernel B: h = relu(agg @ W_rel^T + b_rel + x @ W_root^T), in-place over agg
// ---------------------------------------------------------------------------
#define BLOCK_B 128
__global__ __launch_bounds__(BLOCK_B) void dense_kernel(
    float* __restrict__ aggh,
    const float* __restrict__ x,
    const float* __restrict__ W_rel,
    const float* __restrict__ b_rel,
    const float* __restrict__ W_root)
{
    __shared__ float Wl[128 * 64];
    __shared__ float bl[64];
    int tid = threadIdx.x;
    for (int i = tid; i < 64 * 64; i += BLOCK_B) {
        int k = i >> 6, d = i & 63;
        Wl[i]        = W_rel[d * 64 + k];
        Wl[4096 + i] = W_root[d * 64 + k];
    }
    if (tid < 64) bl[tid] = b_rel[tid];
    __syncthreads();

    int node = blockIdx.x * BLOCK_B + tid;
    if (node >= N_NODES) return;

    float acc[64];
    #pragma unroll
    for (int d = 0; d < 64; ++d) acc[d] = bl[d];

    float* myrow = aggh + (size_t)node * 64;
    const float4* av = reinterpret_cast<const float4*>(myrow);
    const float4* xv = reinterpret_cast<const float4*>(x + (size_t)node * 64);

    #pragma unroll 1
    for (int half = 0; half < 2; ++half) {
        const float4* src = half ? xv : av;
        const float* Wbase = Wl + half * 4096;
        #pragma unroll 1
        for (int kc = 0; kc < 8; ++kc) {
            float4 v0 = src[kc * 2];
            float4 v1 = src[kc * 2 + 1];
            float vv[8] = {v0.x, v0.y, v0.z, v0.w, v1.x, v1.y, v1.z, v1.w};
            #pragma unroll
            for (int j = 0; j < 8; ++j) {
                const float* wrow = Wbase + (kc * 8 + j) * 64;
                #pragma unroll
                for (int d = 0; d < 64; ++d)
                    acc[d] = fmaf(vv[j], wrow[d], acc[d]);
            }
        }
    }

    float4* hv = reinterpret_cast<float4*>(myrow);
    #pragma unroll
    for (int d4 = 0; d4 < 16; ++d4) {
        float4 o;
        o.x = fmaxf(acc[d4 * 4 + 0], 0.f);
        o.y = fmaxf(acc[d4 * 4 + 1], 0.f);
        o.z = fmaxf(acc[d4 * 4 + 2], 0.f);
        o.w = fmaxf(acc[d4 * 4 + 3], 0.f);
        hv[d4] = o;
    }
}

// ---------------------------------------------------------------------------
// Kernel C1: per-(graph, dim) sum(h), sum(h^2), per-graph count
// ---------------------------------------------------------------------------
#define NPW 32
__global__ __launch_bounds__(256) void stats_kernel(
    const float* __restrict__ h,
    const int* __restrict__ batch,
    float* __restrict__ gsum,
    float* __restrict__ gsum2,
    float* __restrict__ gcnt)
{
    int wave = (int)((blockIdx.x * blockDim.x + threadIdx.x) >> 6);
    int lane = threadIdx.x & 63;
    int base = wave * NPW;
    if (base >= N_NODES) return;
    int end = min(base + NPW, N_NODES);

    int gcur = batch[base];
    float s = 0.f, s2 = 0.f, cnt = 0.f;
    for (int n = base; n < end; ++n) {
        int g = batch[n];
        if (g != gcur) {
            atomicAdd(&gsum[gcur * 64 + lane], s);
            atomicAdd(&gsum2[gcur * 64 + lane], s2);
            if (lane == 0) atomicAdd(&gcnt[gcur], cnt);
            s = 0.f; s2 = 0.f; cnt = 0.f;
            gcur = g;
        }
        float v = h[(size_t)n * 64 + lane];
        s += v;
        s2 = fmaf(v, v, s2);
        cnt += 1.f;
    }
    atomicAdd(&gsum[gcur * 64 + lane], s);
    atomicAdd(&gsum2[gcur * 64 + lane], s2);
    if (lane == 0) atomicAdd(&gcnt[gcur], cnt);
}

// ---------------------------------------------------------------------------
// Kernel C2: fold stats into per-(g,d) affine A,B
// ---------------------------------------------------------------------------
__global__ __launch_bounds__(256) void finalize_kernel(
    const float* __restrict__ gsum,
    const float* __restrict__ gsum2,
    const float* __restrict__ gcnt,
    const float* __restrict__ gn_w,
    const float* __restrict__ gn_b,
    const float* __restrict__ gn_ms,
    float* __restrict__ Ag,
    float* __restrict__ Bg)
{
    int i = blockIdx.x * blockDim.x + threadIdx.x;
    if (i >= NUM_GRAPHS * 64) return;
    int g = i >> 6, d = i & 63;
    float c = fmaxf(gcnt[g], 1.f);
    float m = gsum[i] / c;
    float q = gsum2[i] / c;
    float s = gn_ms[d];
    float var = q - (2.f * s - s * s) * m * m;
    float inv = rsqrtf(fmaxf(var, 0.f) + EPS);
    float A = gn_w[d] * inv;
    Ag[i] = A;
    Bg[i] = gn_b[d] - A * s * m;
}

// ---------------------------------------------------------------------------
// Kernel C3: out[n][d] = A[g][d] * h[n][d] + B[g][d]
// ---------------------------------------------------------------------------
__global__ __launch_bounds__(256) void apply_kernel(
    const float* __restrict__ h,
    const int* __restrict__ batch,
    const float* __restrict__ Ag,
    const float* __restrict__ Bg,
    float* __restrict__ out)
{
    long long gid = (long long)blockIdx.x * blockDim.x + threadIdx.x;
    if (gid >= (long long)N_NODES * 16) return;
    int n = (int)(gid >> 4);
    int q = (int)(gid & 15);
    int g = batch[n];
    float4 hv = reinterpret_cast<const float4*>(h)[gid];
    float4 A = reinterpret_cast<const float4*>(Ag)[g * 16 + q];
    float4 B = reinterpret_cast<const float4*>(Bg)[g * 16 + q];
    float4 o;
    o.x = fmaf(A.x, hv.x, B.x);
    o.y = fmaf(A.y, hv.y, B.y);
    o.z = fmaf(A.z, hv.z, B.z);
    o.w = fmaf(A.w, hv.w, B.w);
    reinterpret_cast<float4*>(out)[gid] = o;
}

// ---------------------------------------------------------------------------
extern "C" void kernel_launch(void* const* d_in, const int* in_sizes, int n_in,
                              void* d_out, int out_size, void* d_ws, size_t ws_size,
                              hipStream_t stream)
{
    const float* x      = (const float*)d_in[0];
    const int*   ei     = (const int*)d_in[1];
    const float* ea     = (const float*)d_in[2];
    const int*   batch  = (const int*)d_in[3];
    const float* W_rel  = (const float*)d_in[4];
    const float* b_rel  = (const float*)d_in[5];
    const float* W_root = (const float*)d_in[6];
    const float* gn_w   = (const float*)d_in[7];
    const float* gn_b   = (const float*)d_in[8];
    const float* gn_ms  = (const float*)d_in[9];
    const int* src_idx = ei;
    const int* dst_idx = ei + N_EDGES;

    // ---- workspace layout ----
    // zeroed region: deg (N ints) | gsum (G*64) | gsum2 (G*64) | gcnt (64)
    char* wsp = (char*)d_ws;
    int*   deg     = (int*)wsp;
    float* gsum    = (float*)(deg + N_NODES);
    float* gsum2   = gsum + NUM_GRAPHS * 64;
    float* gcnt    = gsum2 + NUM_GRAPHS * 64;
    size_t zero_bytes = ((size_t)N_NODES + 2 * NUM_GRAPHS * 64 + 64) * 4;

    int*   offsets  = (int*)(gcnt + 64);           // N+1
    int*   blocksum = offsets + N_NODES + 1;       // 64 (NSCAN=49 used)
    int*   blockoff = blocksum + 64;               // 64
    int*   cursor   = blockoff + 64;               // N
    // align csr to 8 bytes
    size_t csr_off = ((size_t)((char*)(cursor + N_NODES) - wsp) + 7) & ~(size_t)7;
    int2*  csr     = (int2*)(wsp + csr_off);       // E
    float* agg     = (float*)(csr + N_EDGES);      // N*64
    float* Ag      = agg + (size_t)N_NODES * 64;   // G*64
    float* Bg      = Ag + NUM_GRAPHS * 64;         // G*64
    size_t required = (size_t)((char*)(Bg + NUM_GRAPHS * 64) - wsp);

    bool use_csr = (ws_size >= required);

    if (use_csr) {
        hipMemsetAsync(d_ws, 0, zero_bytes, stream);
        hist_kernel<<<(N_EDGES + 255) / 256, 256, 0, stream>>>(dst_idx, deg);
        scan1_kernel<<<NSCAN, SCAN_T, 0, stream>>>(deg, offsets, blocksum);
        scan2_kernel<<<1, 64, 0, stream>>>(blocksum, blockoff);
        scan3_kernel<<<(N_NODES + 255) / 256, 256, 0, stream>>>(offsets, blockoff, cursor);
        fill_kernel<<<(N_EDGES + 255) / 256, 256, 0, stream>>>(src_idx, dst_idx, ea, cursor, csr);
        gather_kernel<<<(N_NODES + 3) / 4, 256, 0, stream>>>(x, offsets, csr, agg);
    } else {
        // fallback: atomic scatter into agg placed right after the stats
        agg = (float*)(gcnt + 64);
        Ag  = agg + (size_t)N_NODES * 64;
        Bg  = Ag + NUM_GRAPHS * 64;
        size_t zb = zero_bytes + (size_t)N_NODES * 64 * 4;
        hipMemsetAsync(d_ws, 0, zb, stream);
        long long total = (long long)N_EDGES * 16;
        scatter_kernel<<<(int)((total + 255) / 256), 256, 0, stream>>>(
            x, src_idx, dst_idx, ea, agg);
    }

    dense_kernel<<<(N_NODES + BLOCK_B - 1) / BLOCK_B, BLOCK_B, 0, stream>>>(
        agg, x, W_rel, b_rel, W_root);

    {
        int waves = (N_NODES + NPW - 1) / NPW;
        stats_kernel<<<(waves + 3) / 4, 256, 0, stream>>>(agg, batch, gsum, gsum2, gcnt);
    }
    finalize_kernel<<<(NUM_GRAPHS * 64 + 255) / 256, 256, 0, stream>>>(
        gsum, gsum2, gcnt, gn_w, gn_b, gn_ms, Ag, Bg);
    {
        long long total = (long long)N_NODES * 16;
        apply_kernel<<<(int)((total + 255) / 256), 256, 0, stream>>>(
            agg, batch, Ag, Bg, (float*)d_out);
    }
}

// Round 3
// 233.652 us; speedup vs baseline: 6.2696x; 1.5983x over previous
//
#include <hip/hip_runtime.h>

#define N_NODES 100000
#define N_EDGES 1600000
#define D 64
#define NUM_GRAPHS 64
#define EPS 1e-5f

// ---- bucketed CSR build params ----
#define BSHIFT 9
#define NPB 512                                   // nodes per bucket
#define NBUCKETS ((N_NODES + NPB - 1) / NPB)      // 196
#define A_THREADS 1024
#define A_EPT 8
#define A_CHUNK (A_THREADS * A_EPT)               // 8192
#define NBLK_A ((N_EDGES + A_CHUNK - 1) / A_CHUNK) // 196

// ---- legacy scan params (fallback path) ----
#define SCAN_T 256
#define SCAN_E 8
#define SCAN_CHUNK (SCAN_T * SCAN_E)
#define NSCAN ((N_NODES + SCAN_CHUNK - 1) / SCAN_CHUNK)

// ===========================================================================
// NEW PATH kernel 1: per-bucket edge counts
// ===========================================================================
__global__ __launch_bounds__(A_THREADS) void countA_kernel(
    const int* __restrict__ dst_idx, int* __restrict__ bucket_cnt)
{
    __shared__ int hist[NBUCKETS];
    int tid = threadIdx.x;
    if (tid < NBUCKETS) hist[tid] = 0;
    __syncthreads();
    int base = blockIdx.x * A_CHUNK;
    #pragma unroll
    for (int i = 0; i < A_EPT; ++i) {
        int e = base + i * A_THREADS + tid;
        if (e < N_EDGES) atomicAdd(&hist[dst_idx[e] >> BSHIFT], 1);
    }
    __syncthreads();
    if (tid < NBUCKETS && hist[tid] > 0) atomicAdd(&bucket_cnt[tid], hist[tid]);
}

// ===========================================================================
// NEW PATH kernel 2: scan 196 bucket counts -> base + cursor
// ===========================================================================
__global__ __launch_bounds__(256) void scanA_kernel(
    const int* __restrict__ bucket_cnt, int* __restrict__ bucket_base,
    int* __restrict__ bucket_cursor, int* __restrict__ offsets)
{
    __shared__ int p[256];
    int tid = threadIdx.x;
    int c = (tid < NBUCKETS) ? bucket_cnt[tid] : 0;
    p[tid] = c;
    __syncthreads();
    for (int off = 1; off < 256; off <<= 1) {
        int v = p[tid];
        int a = (tid >= off) ? p[tid - off] : 0;
        __syncthreads();
        p[tid] = v + a;
        __syncthreads();
    }
    int ex = (tid == 0) ? 0 : p[tid - 1];
    if (tid < NBUCKETS) {
        bucket_base[tid] = ex;
        bucket_cursor[tid] = ex;
    }
    if (tid == 0) {
        bucket_base[NBUCKETS] = N_EDGES;
        offsets[N_NODES] = N_EDGES;
    }
}

// ===========================================================================
// NEW PATH kernel 3: bin edges by bucket (contiguous runs per block)
// packed entry: .x = src | (dst&511)<<17 ; .y = weight bits
// ===========================================================================
__global__ __launch_bounds__(A_THREADS) void binA_kernel(
    const int* __restrict__ src_idx, const int* __restrict__ dst_idx,
    const float* __restrict__ ea, int* __restrict__ bucket_cursor,
    int2* __restrict__ binned)
{
    __shared__ int hist[NBUCKETS];
    __shared__ int lbase[NBUCKETS];
    int tid = threadIdx.x;
    if (tid < NBUCKETS) hist[tid] = 0;
    __syncthreads();

    int base = blockIdx.x * A_CHUNK;
    int srcv[A_EPT], dstv[A_EPT];
    float wv[A_EPT];
    #pragma unroll
    for (int i = 0; i < A_EPT; ++i) {
        int e = base + i * A_THREADS + tid;
        if (e < N_EDGES) {
            srcv[i] = src_idx[e];
            dstv[i] = dst_idx[e];
            wv[i]   = ea[e];
            atomicAdd(&hist[dstv[i] >> BSHIFT], 1);
        } else {
            dstv[i] = -1; srcv[i] = 0; wv[i] = 0.f;
        }
    }
    __syncthreads();
    if (tid < NBUCKETS) lbase[tid] = atomicAdd(&bucket_cursor[tid], hist[tid]);
    __syncthreads();
    if (tid < NBUCKETS) hist[tid] = 0;
    __syncthreads();
    #pragma unroll
    for (int i = 0; i < A_EPT; ++i) {
        if (dstv[i] >= 0) {
            int b = dstv[i] >> BSHIFT;
            int r = atomicAdd(&hist[b], 1);
            binned[lbase[b] + r] =
                make_int2(srcv[i] | ((dstv[i] & (NPB - 1)) << 17),
                          __float_as_int(wv[i]));
        }
    }
}

// ===========================================================================
// NEW PATH kernel 4: per-bucket local counting sort -> offsets[] + csr[]
// One block per bucket; all scattered writes confined to this bucket's
// ~64 KB csr region (single XCD L2 -> full-line merging).
// ===========================================================================
__global__ __launch_bounds__(256) void binB_kernel(
    const int2* __restrict__ binned, const int* __restrict__ bucket_base,
    int* __restrict__ offsets, int2* __restrict__ csr)
{
    __shared__ int dcnt[NPB];
    __shared__ int doff[NPB];
    __shared__ int psum[256];
    int tid = threadIdx.x;
    int b = blockIdx.x;
    int beg = bucket_base[b];
    int end = bucket_base[b + 1];

    for (int i = tid; i < NPB; i += 256) dcnt[i] = 0;
    __syncthreads();
    for (int j = beg + tid; j < end; j += 256) {
        int px = binned[j].x;
        atomicAdd(&dcnt[px >> 17], 1);
    }
    __syncthreads();
    // exclusive scan of dcnt[0..511]
    int e0 = dcnt[2 * tid], e1 = dcnt[2 * tid + 1];
    psum[tid] = e0 + e1;
    __syncthreads();
    for (int off = 1; off < 256; off <<= 1) {
        int v = psum[tid];
        int a = (tid >= off) ? psum[tid - off] : 0;
        __syncthreads();
        psum[tid] = v + a;
        __syncthreads();
    }
    int ex = (tid == 0) ? 0 : psum[tid - 1];
    doff[2 * tid] = ex;
    doff[2 * tid + 1] = ex + e0;
    __syncthreads();
    // write global offsets + init cursors
    for (int i = tid; i < NPB; i += 256) {
        int node = (b << BSHIFT) + i;
        if (node < N_NODES) offsets[node] = beg + doff[i];
        dcnt[i] = doff[i];
    }
    __syncthreads();
    // scatter within bucket region
    for (int j = beg + tid; j < end; j += 256) {
        int2 v = binned[j];
        int dlo = v.x >> 17;
        int r = atomicAdd(&dcnt[dlo], 1);
        csr[beg + r] = make_int2(v.x & 0x1FFFF, v.y);
    }
}

// ===========================================================================
// Gather-aggregate: one wave per node, lane = dim
// ===========================================================================
__global__ __launch_bounds__(256) void gather_kernel(
    const float* __restrict__ x, const int* __restrict__ offsets,
    const int2* __restrict__ csr, float* __restrict__ agg)
{
    int wid = (int)((blockIdx.x * blockDim.x + threadIdx.x) >> 6);
    if (wid >= N_NODES) return;
    int lane = threadIdx.x & 63;
    int beg = __builtin_amdgcn_readfirstlane(offsets[wid]);
    int end = __builtin_amdgcn_readfirstlane(offsets[wid + 1]);
    float acc0 = 0.f, acc1 = 0.f;
    int j = beg;
    for (; j + 1 < end; j += 2) {
        int2 a = csr[j];
        int2 b = csr[j + 1];
        acc0 = fmaf(__int_as_float(a.y), x[(size_t)a.x * 64 + lane], acc0);
        acc1 = fmaf(__int_as_float(b.y), x[(size_t)b.x * 64 + lane], acc1);
    }
    if (j < end) {
        int2 a = csr[j];
        acc0 = fmaf(__int_as_float(a.y), x[(size_t)a.x * 64 + lane], acc0);
    }
    agg[(size_t)wid * 64 + lane] = acc0 + acc1;
}

// ===========================================================================
// LEGACY PATH (fallback tier 2): hist + 3-kernel scan + atomic fill
// ===========================================================================
__global__ __launch_bounds__(256) void hist_kernel(
    const int* __restrict__ dst_idx, int* __restrict__ deg)
{
    int e = blockIdx.x * blockDim.x + threadIdx.x;
    if (e >= N_EDGES) return;
    atomicAdd(&deg[dst_idx[e]], 1);
}

__global__ __launch_bounds__(SCAN_T) void scan1_kernel(
    const int* __restrict__ deg, int* __restrict__ offsets,
    int* __restrict__ blocksum)
{
    __shared__ int lds[SCAN_T];
    int b = blockIdx.x, t = threadIdx.x;
    int base = b * SCAN_CHUNK + t * SCAN_E;
    int v[SCAN_E];
    int s = 0;
    #pragma unroll
    for (int i = 0; i < SCAN_E; ++i) {
        v[i] = (base + i < N_NODES) ? deg[base + i] : 0;
        s += v[i];
    }
    lds[t] = s;
    __syncthreads();
    for (int off = 1; off < SCAN_T; off <<= 1) {
        int val = lds[t];
        int add = (t >= off) ? lds[t - off] : 0;
        __syncthreads();
        lds[t] = val + add;
        __syncthreads();
    }
    if (t == SCAN_T - 1) blocksum[b] = lds[SCAN_T - 1];
    int run = (t == 0) ? 0 : lds[t - 1];
    #pragma unroll
    for (int i = 0; i < SCAN_E; ++i) {
        if (base + i < N_NODES) offsets[base + i] = run;
        run += v[i];
    }
}

__global__ __launch_bounds__(64) void scan2_kernel(
    const int* __restrict__ blocksum, int* __restrict__ blockoff)
{
    __shared__ int lds[64];
    int t = threadIdx.x;
    lds[t] = (t < NSCAN) ? blocksum[t] : 0;
    __syncthreads();
    for (int off = 1; off < 64; off <<= 1) {
        int val = lds[t];
        int add = (t >= off) ? lds[t - off] : 0;
        __syncthreads();
        lds[t] = val + add;
        __syncthreads();
    }
    if (t < NSCAN) blockoff[t] = (t == 0) ? 0 : lds[t - 1];
}

__global__ __launch_bounds__(256) void scan3_kernel(
    int* __restrict__ offsets, const int* __restrict__ blockoff,
    int* __restrict__ cursor)
{
    int i = blockIdx.x * blockDim.x + threadIdx.x;
    if (i < N_NODES) {
        int v = offsets[i] + blockoff[i / SCAN_CHUNK];
        offsets[i] = v;
        cursor[i] = v;
    }
    if (i == 0) offsets[N_NODES] = N_EDGES;
}

__global__ __launch_bounds__(256) void fill_kernel(
    const int* __restrict__ src_idx, const int* __restrict__ dst_idx,
    const float* __restrict__ ea, int* __restrict__ cursor,
    int2* __restrict__ csr)
{
    int e = blockIdx.x * blockDim.x + threadIdx.x;
    if (e >= N_EDGES) return;
    int s = src_idx[e];
    int d = dst_idx[e];
    float w = ea[e];
    int pos = atomicAdd(&cursor[d], 1);
    csr[pos] = make_int2(s, __float_as_int(w));
}

// ===========================================================================
// LAST-RESORT fallback: atomic scatter
// ===========================================================================
__global__ __launch_bounds__(256) void scatter_kernel(
    const float* __restrict__ x,
    const int* __restrict__ src_idx,
    const int* __restrict__ dst_idx,
    const float* __restrict__ ea,
    float* __restrict__ agg)
{
    long long gid = (long long)blockIdx.x * blockDim.x + threadIdx.x;
    if (gid >= (long long)N_EDGES * 16) return;
    int e = (int)(gid >> 4);
    int q = (int)(gid & 15);
    int s = src_idx[e];
    int d = dst_idx[e];
    float w = ea[e];
    float4 v = reinterpret_cast<const float4*>(x)[(size_t)s * 16 + q];
    float* out = agg + (size_t)d * 64 + q * 4;
    atomicAdd(out + 0, w * v.x);
    atomicAdd(out + 1, w * v.y);
    atomicAdd(out + 2, w * v.z);
    atomicAdd(out + 3, w * v.w);
}

// ===========================================================================
// Kernel B: h = relu(agg @ W_rel^T + b_rel + x @ W_root^T), in-place
// ===========================================================================
#define BLOCK_B 128
__global__ __launch_bounds__(BLOCK_B) void dense_kernel(
    float* __restrict__ aggh,
    const float* __restrict__ x,
    const float* __restrict__ W_rel,
    const float* __restrict__ b_rel,
    const float* __restrict__ W_root)
{
    __shared__ float Wl[128 * 64];
    __shared__ float bl[64];
    int tid = threadIdx.x;
    for (int i = tid; i < 64 * 64; i += BLOCK_B) {
        int k = i >> 6, d = i & 63;
        Wl[i]        = W_rel[d * 64 + k];
        Wl[4096 + i] = W_root[d * 64 + k];
    }
    if (tid < 64) bl[tid] = b_rel[tid];
    __syncthreads();

    int node = blockIdx.x * BLOCK_B + tid;
    if (node >= N_NODES) return;

    float acc[64];
    #pragma unroll
    for (int d = 0; d < 64; ++d) acc[d] = bl[d];

    float* myrow = aggh + (size_t)node * 64;
    const float4* av = reinterpret_cast<const float4*>(myrow);
    const float4* xv = reinterpret_cast<const float4*>(x + (size_t)node * 64);

    #pragma unroll 1
    for (int half = 0; half < 2; ++half) {
        const float4* src = half ? xv : av;
        const float* Wbase = Wl + half * 4096;
        #pragma unroll 1
        for (int kc = 0; kc < 8; ++kc) {
            float4 v0 = src[kc * 2];
            float4 v1 = src[kc * 2 + 1];
            float vv[8] = {v0.x, v0.y, v0.z, v0.w, v1.x, v1.y, v1.z, v1.w};
            #pragma unroll
            for (int j = 0; j < 8; ++j) {
                const float* wrow = Wbase + (kc * 8 + j) * 64;
                #pragma unroll
                for (int d = 0; d < 64; ++d)
                    acc[d] = fmaf(vv[j], wrow[d], acc[d]);
            }
        }
    }

    float4* hv = reinterpret_cast<float4*>(myrow);
    #pragma unroll
    for (int d4 = 0; d4 < 16; ++d4) {
        float4 o;
        o.x = fmaxf(acc[d4 * 4 + 0], 0.f);
        o.y = fmaxf(acc[d4 * 4 + 1], 0.f);
        o.z = fmaxf(acc[d4 * 4 + 2], 0.f);
        o.w = fmaxf(acc[d4 * 4 + 3], 0.f);
        hv[d4] = o;
    }
}

// ===========================================================================
// Kernel C1: per-(graph, dim) sum(h), sum(h^2), per-graph count
// ===========================================================================
#define NPW 32
__global__ __launch_bounds__(256) void stats_kernel(
    const float* __restrict__ h,
    const int* __restrict__ batch,
    float* __restrict__ gsum,
    float* __restrict__ gsum2,
    float* __restrict__ gcnt)
{
    int wave = (int)((blockIdx.x * blockDim.x + threadIdx.x) >> 6);
    int lane = threadIdx.x & 63;
    int base = wave * NPW;
    if (base >= N_NODES) return;
    int end = min(base + NPW, N_NODES);

    int gcur = batch[base];
    float s = 0.f, s2 = 0.f, cnt = 0.f;
    for (int n = base; n < end; ++n) {
        int g = batch[n];
        if (g != gcur) {
            atomicAdd(&gsum[gcur * 64 + lane], s);
            atomicAdd(&gsum2[gcur * 64 + lane], s2);
            if (lane == 0) atomicAdd(&gcnt[gcur], cnt);
            s = 0.f; s2 = 0.f; cnt = 0.f;
            gcur = g;
        }
        float v = h[(size_t)n * 64 + lane];
        s += v;
        s2 = fmaf(v, v, s2);
        cnt += 1.f;
    }
    atomicAdd(&gsum[gcur * 64 + lane], s);
    atomicAdd(&gsum2[gcur * 64 + lane], s2);
    if (lane == 0) atomicAdd(&gcnt[gcur], cnt);
}

// ===========================================================================
// Kernel C2: fold stats into per-(g,d) affine A,B
// ===========================================================================
__global__ __launch_bounds__(256) void finalize_kernel(
    const float* __restrict__ gsum,
    const float* __restrict__ gsum2,
    const float* __restrict__ gcnt,
    const float* __restrict__ gn_w,
    const float* __restrict__ gn_b,
    const float* __restrict__ gn_ms,
    float* __restrict__ Ag,
    float* __restrict__ Bg)
{
    int i = blockIdx.x * blockDim.x + threadIdx.x;
    if (i >= NUM_GRAPHS * 64) return;
    int g = i >> 6, d = i & 63;
    float c = fmaxf(gcnt[g], 1.f);
    float m = gsum[i] / c;
    float q = gsum2[i] / c;
    float s = gn_ms[d];
    float var = q - (2.f * s - s * s) * m * m;
    float inv = rsqrtf(fmaxf(var, 0.f) + EPS);
    float A = gn_w[d] * inv;
    Ag[i] = A;
    Bg[i] = gn_b[d] - A * s * m;
}

// ===========================================================================
// Kernel C3: out[n][d] = A[g][d] * h[n][d] + B[g][d]
// ===========================================================================
__global__ __launch_bounds__(256) void apply_kernel(
    const float* __restrict__ h,
    const int* __restrict__ batch,
    const float* __restrict__ Ag,
    const float* __restrict__ Bg,
    float* __restrict__ out)
{
    long long gid = (long long)blockIdx.x * blockDim.x + threadIdx.x;
    if (gid >= (long long)N_NODES * 16) return;
    int n = (int)(gid >> 4);
    int q = (int)(gid & 15);
    int g = batch[n];
    float4 hv = reinterpret_cast<const float4*>(h)[gid];
    float4 A = reinterpret_cast<const float4*>(Ag)[g * 16 + q];
    float4 B = reinterpret_cast<const float4*>(Bg)[g * 16 + q];
    float4 o;
    o.x = fmaf(A.x, hv.x, B.x);
    o.y = fmaf(A.y, hv.y, B.y);
    o.z = fmaf(A.z, hv.z, B.z);
    o.w = fmaf(A.w, hv.w, B.w);
    reinterpret_cast<float4*>(out)[gid] = o;
}

// ===========================================================================
extern "C" void kernel_launch(void* const* d_in, const int* in_sizes, int n_in,
                              void* d_out, int out_size, void* d_ws, size_t ws_size,
                              hipStream_t stream)
{
    const float* x      = (const float*)d_in[0];
    const int*   ei     = (const int*)d_in[1];
    const float* ea     = (const float*)d_in[2];
    const int*   batch  = (const int*)d_in[3];
    const float* W_rel  = (const float*)d_in[4];
    const float* b_rel  = (const float*)d_in[5];
    const float* W_root = (const float*)d_in[6];
    const float* gn_w   = (const float*)d_in[7];
    const float* gn_b   = (const float*)d_in[8];
    const float* gn_ms  = (const float*)d_in[9];
    const int* src_idx = ei;
    const int* dst_idx = ei + N_EDGES;

    char* wsp = (char*)d_ws;

    // ---------------- NEW path layout ----------------
    // zeroed: bucket_cnt(256) | gsum(G*64) | gsum2(G*64) | gcnt(64)
    int*   bucket_cnt  = (int*)wsp;
    float* gsumN       = (float*)(bucket_cnt + 256);
    float* gsum2N      = gsumN + NUM_GRAPHS * 64;
    float* gcntN       = gsum2N + NUM_GRAPHS * 64;
    size_t zeroN       = ((size_t)256 + 2 * NUM_GRAPHS * 64 + 64) * 4;
    int*   bucket_base = (int*)(gcntN + 64);            // NBUCKETS+1 (pad 256)
    int*   bucket_cur  = bucket_base + 256;             // NBUCKETS (pad 256)
    int*   offsetsN    = bucket_cur + 256;              // N+1
    size_t binned_off  = (((size_t)((char*)(offsetsN + N_NODES + 1) - wsp)) + 15) & ~(size_t)15;
    int2*  binned      = (int2*)(wsp + binned_off);     // E
    int2*  csrN        = binned + N_EDGES;              // E
    float* aggN        = (float*)(csrN + N_EDGES);      // N*64
    float* AgN         = aggN + (size_t)N_NODES * 64;
    float* BgN         = AgN + NUM_GRAPHS * 64;
    size_t reqN        = (size_t)((char*)(BgN + NUM_GRAPHS * 64) - wsp);

    // ---------------- legacy CSR layout ----------------
    int*   degL     = (int*)wsp;
    float* gsumL    = (float*)(degL + N_NODES);
    float* gsum2L   = gsumL + NUM_GRAPHS * 64;
    float* gcntL    = gsum2L + NUM_GRAPHS * 64;
    size_t zeroL    = ((size_t)N_NODES + 2 * NUM_GRAPHS * 64 + 64) * 4;
    int*   offsetsL = (int*)(gcntL + 64);
    int*   blocksum = offsetsL + N_NODES + 1;
    int*   blockoff = blocksum + 64;
    int*   cursorL  = blockoff + 64;
    size_t csrL_off = (((size_t)((char*)(cursorL + N_NODES) - wsp)) + 15) & ~(size_t)15;
    int2*  csrL     = (int2*)(wsp + csrL_off);
    float* aggL     = (float*)(csrL + N_EDGES);
    float* AgL      = aggL + (size_t)N_NODES * 64;
    float* BgL      = AgL + NUM_GRAPHS * 64;
    size_t reqL     = (size_t)((char*)(BgL + NUM_GRAPHS * 64) - wsp);

    float *agg, *gsum, *gsum2, *gcnt, *Ag, *Bg;

    if (ws_size >= reqN) {
        // -------- new bucketed build --------
        hipMemsetAsync(d_ws, 0, zeroN, stream);
        countA_kernel<<<NBLK_A, A_THREADS, 0, stream>>>(dst_idx, bucket_cnt);
        scanA_kernel<<<1, 256, 0, stream>>>(bucket_cnt, bucket_base, bucket_cur, offsetsN);
        binA_kernel<<<NBLK_A, A_THREADS, 0, stream>>>(src_idx, dst_idx, ea, bucket_cur, binned);
        binB_kernel<<<NBUCKETS, 256, 0, stream>>>(binned, bucket_base, offsetsN, csrN);
        gather_kernel<<<(N_NODES + 3) / 4, 256, 0, stream>>>(x, offsetsN, csrN, aggN);
        agg = aggN; gsum = gsumN; gsum2 = gsum2N; gcnt = gcntN; Ag = AgN; Bg = BgN;
    } else if (ws_size >= reqL) {
        // -------- legacy CSR build --------
        hipMemsetAsync(d_ws, 0, zeroL, stream);
        hist_kernel<<<(N_EDGES + 255) / 256, 256, 0, stream>>>(dst_idx, degL);
        scan1_kernel<<<NSCAN, SCAN_T, 0, stream>>>(degL, offsetsL, blocksum);
        scan2_kernel<<<1, 64, 0, stream>>>(blocksum, blockoff);
        scan3_kernel<<<(N_NODES + 255) / 256, 256, 0, stream>>>(offsetsL, blockoff, cursorL);
        fill_kernel<<<(N_EDGES + 255) / 256, 256, 0, stream>>>(src_idx, dst_idx, ea, cursorL, csrL);
        gather_kernel<<<(N_NODES + 3) / 4, 256, 0, stream>>>(x, offsetsL, csrL, aggL);
        agg = aggL; gsum = gsumL; gsum2 = gsum2L; gcnt = gcntL; Ag = AgL; Bg = BgL;
    } else {
        // -------- atomic scatter fallback --------
        agg   = (float*)(gcntL + 64);
        Ag    = agg + (size_t)N_NODES * 64;
        Bg    = Ag + NUM_GRAPHS * 64;
        gsum = gsumL; gsum2 = gsum2L; gcnt = gcntL;
        size_t zb = zeroL + (size_t)N_NODES * 64 * 4;
        hipMemsetAsync(d_ws, 0, zb, stream);
        long long total = (long long)N_EDGES * 16;
        scatter_kernel<<<(int)((total + 255) / 256), 256, 0, stream>>>(
            x, src_idx, dst_idx, ea, agg);
    }

    dense_kernel<<<(N_NODES + BLOCK_B - 1) / BLOCK_B, BLOCK_B, 0, stream>>>(
        agg, x, W_rel, b_rel, W_root);
    {
        int waves = (N_NODES + NPW - 1) / NPW;
        stats_kernel<<<(waves + 3) / 4, 256, 0, stream>>>(agg, batch, gsum, gsum2, gcnt);
    }
    finalize_kernel<<<(NUM_GRAPHS * 64 + 255) / 256, 256, 0, stream>>>(
        gsum, gsum2, gcnt, gn_w, gn_b, gn_ms, Ag, Bg);
    {
        long long total = (long long)N_NODES * 16;
        apply_kernel<<<(int)((total + 255) / 256), 256, 0, stream>>>(
            agg, batch, Ag, Bg, (float*)d_out);
    }
}

// Round 4
// 196.560 us; speedup vs baseline: 7.4528x; 1.1887x over previous
//
#include <hip/hip_runtime.h>

#define N_NODES 100000
#define N_EDGES 1600000
#define D 64
#define NUM_GRAPHS 64
#define EPS 1e-5f

// ---- bucketed CSR build params ----
#define BSHIFT 9
#define NPB 512
#define NBUCKETS ((N_NODES + NPB - 1) / NPB)      // 196
#define A_THREADS 1024
#define A_EPT 8
#define A_CHUNK (A_THREADS * A_EPT)               // 8192
#define NBLK_A ((N_EDGES + A_CHUNK - 1) / A_CHUNK) // 196

// ---- legacy scan params (fallback path) ----
#define SCAN_T 256
#define SCAN_E 8
#define SCAN_CHUNK (SCAN_T * SCAN_E)
#define NSCAN ((N_NODES + SCAN_CHUNK - 1) / SCAN_CHUNK)

typedef float f32x4 __attribute__((ext_vector_type(4)));
typedef short bf16x8 __attribute__((ext_vector_type(8)));

// ===========================================================================
// NEW PATH kernel 1: per-bucket edge counts
// ===========================================================================
__global__ __launch_bounds__(A_THREADS) void countA_kernel(
    const int* __restrict__ dst_idx, int* __restrict__ bucket_cnt)
{
    __shared__ int hist[NBUCKETS];
    int tid = threadIdx.x;
    if (tid < NBUCKETS) hist[tid] = 0;
    __syncthreads();
    int base = blockIdx.x * A_CHUNK;
    #pragma unroll
    for (int i = 0; i < A_EPT; ++i) {
        int e = base + i * A_THREADS + tid;
        if (e < N_EDGES) atomicAdd(&hist[dst_idx[e] >> BSHIFT], 1);
    }
    __syncthreads();
    if (tid < NBUCKETS && hist[tid] > 0) atomicAdd(&bucket_cnt[tid], hist[tid]);
}

// ===========================================================================
// NEW PATH kernel 2: scan 196 bucket counts -> base + cursor
// ===========================================================================
__global__ __launch_bounds__(256) void scanA_kernel(
    const int* __restrict__ bucket_cnt, int* __restrict__ bucket_base,
    int* __restrict__ bucket_cursor, int* __restrict__ offsets)
{
    __shared__ int p[256];
    int tid = threadIdx.x;
    int c = (tid < NBUCKETS) ? bucket_cnt[tid] : 0;
    p[tid] = c;
    __syncthreads();
    for (int off = 1; off < 256; off <<= 1) {
        int v = p[tid];
        int a = (tid >= off) ? p[tid - off] : 0;
        __syncthreads();
        p[tid] = v + a;
        __syncthreads();
    }
    int ex = (tid == 0) ? 0 : p[tid - 1];
    if (tid < NBUCKETS) {
        bucket_base[tid] = ex;
        bucket_cursor[tid] = ex;
    }
    if (tid == 0) {
        bucket_base[NBUCKETS] = N_EDGES;
        offsets[N_NODES] = N_EDGES;
    }
}

// ===========================================================================
// NEW PATH kernel 3: bin edges by bucket
// packed entry: .x = src | (dst&511)<<17 ; .y = weight bits
// ===========================================================================
__global__ __launch_bounds__(A_THREADS) void binA_kernel(
    const int* __restrict__ src_idx, const int* __restrict__ dst_idx,
    const float* __restrict__ ea, int* __restrict__ bucket_cursor,
    int2* __restrict__ binned)
{
    __shared__ int hist[NBUCKETS];
    __shared__ int lbase[NBUCKETS];
    int tid = threadIdx.x;
    if (tid < NBUCKETS) hist[tid] = 0;
    __syncthreads();

    int base = blockIdx.x * A_CHUNK;
    int srcv[A_EPT], dstv[A_EPT];
    float wv[A_EPT];
    #pragma unroll
    for (int i = 0; i < A_EPT; ++i) {
        int e = base + i * A_THREADS + tid;
        if (e < N_EDGES) {
            srcv[i] = src_idx[e];
            dstv[i] = dst_idx[e];
            wv[i]   = ea[e];
            atomicAdd(&hist[dstv[i] >> BSHIFT], 1);
        } else {
            dstv[i] = -1; srcv[i] = 0; wv[i] = 0.f;
        }
    }
    __syncthreads();
    if (tid < NBUCKETS) lbase[tid] = atomicAdd(&bucket_cursor[tid], hist[tid]);
    __syncthreads();
    if (tid < NBUCKETS) hist[tid] = 0;
    __syncthreads();
    #pragma unroll
    for (int i = 0; i < A_EPT; ++i) {
        if (dstv[i] >= 0) {
            int b = dstv[i] >> BSHIFT;
            int r = atomicAdd(&hist[b], 1);
            binned[lbase[b] + r] =
                make_int2(srcv[i] | ((dstv[i] & (NPB - 1)) << 17),
                          __float_as_int(wv[i]));
        }
    }
}

// ===========================================================================
// NEW PATH kernel 4: per-bucket local counting sort -> offsets[] + csr[]
// ===========================================================================
__global__ __launch_bounds__(256) void binB_kernel(
    const int2* __restrict__ binned, const int* __restrict__ bucket_base,
    int* __restrict__ offsets, int2* __restrict__ csr)
{
    __shared__ int dcnt[NPB];
    __shared__ int doff[NPB];
    __shared__ int psum[256];
    int tid = threadIdx.x;
    int b = blockIdx.x;
    int beg = bucket_base[b];
    int end = bucket_base[b + 1];

    for (int i = tid; i < NPB; i += 256) dcnt[i] = 0;
    __syncthreads();
    for (int j = beg + tid; j < end; j += 256) {
        int px = binned[j].x;
        atomicAdd(&dcnt[px >> 17], 1);
    }
    __syncthreads();
    int e0 = dcnt[2 * tid], e1 = dcnt[2 * tid + 1];
    psum[tid] = e0 + e1;
    __syncthreads();
    for (int off = 1; off < 256; off <<= 1) {
        int v = psum[tid];
        int a = (tid >= off) ? psum[tid - off] : 0;
        __syncthreads();
        psum[tid] = v + a;
        __syncthreads();
    }
    int ex = (tid == 0) ? 0 : psum[tid - 1];
    doff[2 * tid] = ex;
    doff[2 * tid + 1] = ex + e0;
    __syncthreads();
    for (int i = tid; i < NPB; i += 256) {
        int node = (b << BSHIFT) + i;
        if (node < N_NODES) offsets[node] = beg + doff[i];
        dcnt[i] = doff[i];
    }
    __syncthreads();
    for (int j = beg + tid; j < end; j += 256) {
        int2 v = binned[j];
        int dlo = v.x >> 17;
        int r = atomicAdd(&dcnt[dlo], 1);
        csr[beg + r] = make_int2(v.x & 0x1FFFF, v.y);
    }
}

// ===========================================================================
// Gather-aggregate: one wave per node, lane = dim
// ===========================================================================
__global__ __launch_bounds__(256) void gather_kernel(
    const float* __restrict__ x, const int* __restrict__ offsets,
    const int2* __restrict__ csr, float* __restrict__ agg)
{
    int wid = (int)((blockIdx.x * blockDim.x + threadIdx.x) >> 6);
    if (wid >= N_NODES) return;
    int lane = threadIdx.x & 63;
    int beg = __builtin_amdgcn_readfirstlane(offsets[wid]);
    int end = __builtin_amdgcn_readfirstlane(offsets[wid + 1]);
    float acc0 = 0.f, acc1 = 0.f;
    int j = beg;
    for (; j + 1 < end; j += 2) {
        int2 a = csr[j];
        int2 b = csr[j + 1];
        acc0 = fmaf(__int_as_float(a.y), x[(size_t)a.x * 64 + lane], acc0);
        acc1 = fmaf(__int_as_float(b.y), x[(size_t)b.x * 64 + lane], acc1);
    }
    if (j < end) {
        int2 a = csr[j];
        acc0 = fmaf(__int_as_float(a.y), x[(size_t)a.x * 64 + lane], acc0);
    }
    agg[(size_t)wid * 64 + lane] = acc0 + acc1;
}

// ===========================================================================
// LEGACY PATH (fallback tier 2)
// ===========================================================================
__global__ __launch_bounds__(256) void hist_kernel(
    const int* __restrict__ dst_idx, int* __restrict__ deg)
{
    int e = blockIdx.x * blockDim.x + threadIdx.x;
    if (e >= N_EDGES) return;
    atomicAdd(&deg[dst_idx[e]], 1);
}

__global__ __launch_bounds__(SCAN_T) void scan1_kernel(
    const int* __restrict__ deg, int* __restrict__ offsets,
    int* __restrict__ blocksum)
{
    __shared__ int lds[SCAN_T];
    int b = blockIdx.x, t = threadIdx.x;
    int base = b * SCAN_CHUNK + t * SCAN_E;
    int v[SCAN_E];
    int s = 0;
    #pragma unroll
    for (int i = 0; i < SCAN_E; ++i) {
        v[i] = (base + i < N_NODES) ? deg[base + i] : 0;
        s += v[i];
    }
    lds[t] = s;
    __syncthreads();
    for (int off = 1; off < SCAN_T; off <<= 1) {
        int val = lds[t];
        int add = (t >= off) ? lds[t - off] : 0;
        __syncthreads();
        lds[t] = val + add;
        __syncthreads();
    }
    if (t == SCAN_T - 1) blocksum[b] = lds[SCAN_T - 1];
    int run = (t == 0) ? 0 : lds[t - 1];
    #pragma unroll
    for (int i = 0; i < SCAN_E; ++i) {
        if (base + i < N_NODES) offsets[base + i] = run;
        run += v[i];
    }
}

__global__ __launch_bounds__(64) void scan2_kernel(
    const int* __restrict__ blocksum, int* __restrict__ blockoff)
{
    __shared__ int lds[64];
    int t = threadIdx.x;
    lds[t] = (t < NSCAN) ? blocksum[t] : 0;
    __syncthreads();
    for (int off = 1; off < 64; off <<= 1) {
        int val = lds[t];
        int add = (t >= off) ? lds[t - off] : 0;
        __syncthreads();
        lds[t] = val + add;
        __syncthreads();
    }
    if (t < NSCAN) blockoff[t] = (t == 0) ? 0 : lds[t - 1];
}

__global__ __launch_bounds__(256) void scan3_kernel(
    int* __restrict__ offsets, const int* __restrict__ blockoff,
    int* __restrict__ cursor)
{
    int i = blockIdx.x * blockDim.x + threadIdx.x;
    if (i < N_NODES) {
        int v = offsets[i] + blockoff[i / SCAN_CHUNK];
        offsets[i] = v;
        cursor[i] = v;
    }
    if (i == 0) offsets[N_NODES] = N_EDGES;
}

__global__ __launch_bounds__(256) void fill_kernel(
    const int* __restrict__ src_idx, const int* __restrict__ dst_idx,
    const float* __restrict__ ea, int* __restrict__ cursor,
    int2* __restrict__ csr)
{
    int e = blockIdx.x * blockDim.x + threadIdx.x;
    if (e >= N_EDGES) return;
    int s = src_idx[e];
    int d = dst_idx[e];
    float w = ea[e];
    int pos = atomicAdd(&cursor[d], 1);
    csr[pos] = make_int2(s, __float_as_int(w));
}

// ===========================================================================
// LAST-RESORT fallback: atomic scatter
// ===========================================================================
__global__ __launch_bounds__(256) void scatter_kernel(
    const float* __restrict__ x,
    const int* __restrict__ src_idx,
    const int* __restrict__ dst_idx,
    const float* __restrict__ ea,
    float* __restrict__ agg)
{
    long long gid = (long long)blockIdx.x * blockDim.x + threadIdx.x;
    if (gid >= (long long)N_EDGES * 16) return;
    int e = (int)(gid >> 4);
    int q = (int)(gid & 15);
    int s = src_idx[e];
    int d = dst_idx[e];
    float w = ea[e];
    float4 v = reinterpret_cast<const float4*>(x)[(size_t)s * 16 + q];
    float* out = agg + (size_t)d * 64 + q * 4;
    atomicAdd(out + 0, w * v.x);
    atomicAdd(out + 1, w * v.y);
    atomicAdd(out + 2, w * v.z);
    atomicAdd(out + 3, w * v.w);
}

// ===========================================================================
// Kernel B (MFMA): h = relu([agg|x] @ [W_rel^T; W_root^T] + b), in-place.
// Split-precision bf16: C = Ah*Bh + Al*Bh + Ah*Bl (fp32-grade accuracy).
// Block: 256 thr = 4 waves; tile 128 nodes x 64 dims; wave: 2x(16-node) tiles.
// A frags loaded straight from global (8 consecutive f32/lane), split in reg.
// B frags pre-split + fragment-ordered in LDS (16B/lane stride, conflict-free).
// ===========================================================================
#define DB 128
__global__ __launch_bounds__(256) void dense_mfma_kernel(
    float* __restrict__ aggh,
    const float* __restrict__ x,
    const float* __restrict__ W_rel,
    const float* __restrict__ b_rel,
    const float* __restrict__ W_root)
{
    __shared__ unsigned int Bf[2][4][4][64][4];   // [hi/lo][kt][dt][lane][4xu32] = 32 KB
    int tid = threadIdx.x;

    // ---- stage B fragments (hi/lo split), 8 quad-groups per thread ----
    #pragma unroll
    for (int g = 0; g < 8; ++g) {
        int q = tid * 8 + g;                 // 0..2047
        int i4   = (q & 1) * 4;              // elem 0 or 4
        int lane = (q >> 1) & 63;
        int dt   = (q >> 7) & 3;
        int kt   = (q >> 9) & 3;
        int d = dt * 16 + (lane & 15);
        int k = kt * 32 + (lane >> 4) * 8 + i4;
        const float* Wsrc = (k < 64) ? (W_rel + d * 64 + k)
                                     : (W_root + d * 64 + (k - 64));
        float4 w = *reinterpret_cast<const float4*>(Wsrc);
        float wf[4] = {w.x, w.y, w.z, w.w};
        unsigned int hi[4], lo[4];
        #pragma unroll
        for (int j = 0; j < 4; ++j) {
            unsigned int bits = __float_as_uint(wf[j]);
            hi[j] = bits >> 16;
            float resid = wf[j] - __uint_as_float(bits & 0xFFFF0000u);
            lo[j] = __float_as_uint(resid) >> 16;
        }
        int u = i4 >> 1;                     // uint slot 0 or 2
        Bf[0][kt][dt][lane][u]     = hi[0] | (hi[1] << 16);
        Bf[0][kt][dt][lane][u + 1] = hi[2] | (hi[3] << 16);
        Bf[1][kt][dt][lane][u]     = lo[0] | (lo[1] << 16);
        Bf[1][kt][dt][lane][u + 1] = lo[2] | (lo[3] << 16);
    }
    __syncthreads();

    int wid = tid >> 6, lane = tid & 63;
    int nbase = blockIdx.x * DB + wid * 32;
    int r = lane & 15;
    int k0 = (lane >> 4) * 8;

    f32x4 acc[2][4];
    #pragma unroll
    for (int nt = 0; nt < 2; ++nt)
        #pragma unroll
        for (int dt = 0; dt < 4; ++dt)
            acc[nt][dt] = (f32x4){0.f, 0.f, 0.f, 0.f};

    #pragma unroll 1
    for (int kt = 0; kt < 4; ++kt) {
        bf16x8 bh[4], bl[4];
        #pragma unroll
        for (int dt = 0; dt < 4; ++dt) {
            bh[dt] = *reinterpret_cast<const bf16x8*>(&Bf[0][kt][dt][lane][0]);
            bl[dt] = *reinterpret_cast<const bf16x8*>(&Bf[1][kt][dt][lane][0]);
        }
        int kk = kt * 32 + k0;               // 0..127
        #pragma unroll
        for (int nt = 0; nt < 2; ++nt) {
            int node = nbase + nt * 16 + r;
            float av[8];
            if (node < N_NODES) {
                const float* srcrow = (kk < 64)
                    ? (aggh + (size_t)node * 64 + kk)
                    : (x + (size_t)node * 64 + (kk - 64));
                float4 v0 = reinterpret_cast<const float4*>(srcrow)[0];
                float4 v1 = reinterpret_cast<const float4*>(srcrow)[1];
                av[0] = v0.x; av[1] = v0.y; av[2] = v0.z; av[3] = v0.w;
                av[4] = v1.x; av[5] = v1.y; av[6] = v1.z; av[7] = v1.w;
            } else {
                #pragma unroll
                for (int i = 0; i < 8; ++i) av[i] = 0.f;
            }
            bf16x8 ah, al;
            #pragma unroll
            for (int i = 0; i < 8; ++i) {
                unsigned int bits = __float_as_uint(av[i]);
                ah[i] = (short)(bits >> 16);
                float resid = av[i] - __uint_as_float(bits & 0xFFFF0000u);
                al[i] = (short)(__float_as_uint(resid) >> 16);
            }
            #pragma unroll
            for (int dt = 0; dt < 4; ++dt) {
                acc[nt][dt] = __builtin_amdgcn_mfma_f32_16x16x32_bf16(ah, bh[dt], acc[nt][dt], 0, 0, 0);
                acc[nt][dt] = __builtin_amdgcn_mfma_f32_16x16x32_bf16(al, bh[dt], acc[nt][dt], 0, 0, 0);
                acc[nt][dt] = __builtin_amdgcn_mfma_f32_16x16x32_bf16(ah, bl[dt], acc[nt][dt], 0, 0, 0);
            }
        }
    }

    // epilogue: bias + relu + store (C layout: col=lane&15, row=(lane>>4)*4+reg)
    int rowg = (lane >> 4) * 4;
    #pragma unroll
    for (int dt = 0; dt < 4; ++dt) {
        int d = dt * 16 + r;
        float bias = b_rel[d];
        #pragma unroll
        for (int nt = 0; nt < 2; ++nt) {
            #pragma unroll
            for (int reg = 0; reg < 4; ++reg) {
                int node = nbase + nt * 16 + rowg + reg;
                if (node < N_NODES) {
                    float v = fmaxf(acc[nt][dt][reg] + bias, 0.f);
                    aggh[(size_t)node * 64 + d] = v;
                }
            }
        }
    }
}

// ===========================================================================
// Kernel C1: per-(graph, dim) sum(h), sum(h^2), per-graph count
// ===========================================================================
#define NPW 32
__global__ __launch_bounds__(256) void stats_kernel(
    const float* __restrict__ h,
    const int* __restrict__ batch,
    float* __restrict__ gsum,
    float* __restrict__ gsum2,
    float* __restrict__ gcnt)
{
    int wave = (int)((blockIdx.x * blockDim.x + threadIdx.x) >> 6);
    int lane = threadIdx.x & 63;
    int base = wave * NPW;
    if (base >= N_NODES) return;
    int end = min(base + NPW, N_NODES);

    int gcur = batch[base];
    float s = 0.f, s2 = 0.f, cnt = 0.f;
    for (int n = base; n < end; ++n) {
        int g = batch[n];
        if (g != gcur) {
            atomicAdd(&gsum[gcur * 64 + lane], s);
            atomicAdd(&gsum2[gcur * 64 + lane], s2);
            if (lane == 0) atomicAdd(&gcnt[gcur], cnt);
            s = 0.f; s2 = 0.f; cnt = 0.f;
            gcur = g;
        }
        float v = h[(size_t)n * 64 + lane];
        s += v;
        s2 = fmaf(v, v, s2);
        cnt += 1.f;
    }
    atomicAdd(&gsum[gcur * 64 + lane], s);
    atomicAdd(&gsum2[gcur * 64 + lane], s2);
    if (lane == 0) atomicAdd(&gcnt[gcur], cnt);
}

// ===========================================================================
// Kernel C2: fold stats into per-(g,d) affine A,B
// ===========================================================================
__global__ __launch_bounds__(256) void finalize_kernel(
    const float* __restrict__ gsum,
    const float* __restrict__ gsum2,
    const float* __restrict__ gcnt,
    const float* __restrict__ gn_w,
    const float* __restrict__ gn_b,
    const float* __restrict__ gn_ms,
    float* __restrict__ Ag,
    float* __restrict__ Bg)
{
    int i = blockIdx.x * blockDim.x + threadIdx.x;
    if (i >= NUM_GRAPHS * 64) return;
    int g = i >> 6, d = i & 63;
    float c = fmaxf(gcnt[g], 1.f);
    float m = gsum[i] / c;
    float q = gsum2[i] / c;
    float s = gn_ms[d];
    float var = q - (2.f * s - s * s) * m * m;
    float inv = rsqrtf(fmaxf(var, 0.f) + EPS);
    float A = gn_w[d] * inv;
    Ag[i] = A;
    Bg[i] = gn_b[d] - A * s * m;
}

// ===========================================================================
// Kernel C3: out[n][d] = A[g][d] * h[n][d] + B[g][d]
// ===========================================================================
__global__ __launch_bounds__(256) void apply_kernel(
    const float* __restrict__ h,
    const int* __restrict__ batch,
    const float* __restrict__ Ag,
    const float* __restrict__ Bg,
    float* __restrict__ out)
{
    long long gid = (long long)blockIdx.x * blockDim.x + threadIdx.x;
    if (gid >= (long long)N_NODES * 16) return;
    int n = (int)(gid >> 4);
    int q = (int)(gid & 15);
    int g = batch[n];
    float4 hv = reinterpret_cast<const float4*>(h)[gid];
    float4 A = reinterpret_cast<const float4*>(Ag)[g * 16 + q];
    float4 B = reinterpret_cast<const float4*>(Bg)[g * 16 + q];
    float4 o;
    o.x = fmaf(A.x, hv.x, B.x);
    o.y = fmaf(A.y, hv.y, B.y);
    o.z = fmaf(A.z, hv.z, B.z);
    o.w = fmaf(A.w, hv.w, B.w);
    reinterpret_cast<float4*>(out)[gid] = o;
}

// ===========================================================================
extern "C" void kernel_launch(void* const* d_in, const int* in_sizes, int n_in,
                              void* d_out, int out_size, void* d_ws, size_t ws_size,
                              hipStream_t stream)
{
    const float* x      = (const float*)d_in[0];
    const int*   ei     = (const int*)d_in[1];
    const float* ea     = (const float*)d_in[2];
    const int*   batch  = (const int*)d_in[3];
    const float* W_rel  = (const float*)d_in[4];
    const float* b_rel  = (const float*)d_in[5];
    const float* W_root = (const float*)d_in[6];
    const float* gn_w   = (const float*)d_in[7];
    const float* gn_b   = (const float*)d_in[8];
    const float* gn_ms  = (const float*)d_in[9];
    const int* src_idx = ei;
    const int* dst_idx = ei + N_EDGES;

    char* wsp = (char*)d_ws;

    // ---------------- NEW path layout ----------------
    int*   bucket_cnt  = (int*)wsp;
    float* gsumN       = (float*)(bucket_cnt + 256);
    float* gsum2N      = gsumN + NUM_GRAPHS * 64;
    float* gcntN       = gsum2N + NUM_GRAPHS * 64;
    size_t zeroN       = ((size_t)256 + 2 * NUM_GRAPHS * 64 + 64) * 4;
    int*   bucket_base = (int*)(gcntN + 64);
    int*   bucket_cur  = bucket_base + 256;
    int*   offsetsN    = bucket_cur + 256;
    size_t binned_off  = (((size_t)((char*)(offsetsN + N_NODES + 1) - wsp)) + 15) & ~(size_t)15;
    int2*  binned      = (int2*)(wsp + binned_off);
    int2*  csrN        = binned + N_EDGES;
    float* aggN        = (float*)(csrN + N_EDGES);
    float* AgN         = aggN + (size_t)N_NODES * 64;
    float* BgN         = AgN + NUM_GRAPHS * 64;
    size_t reqN        = (size_t)((char*)(BgN + NUM_GRAPHS * 64) - wsp);

    // ---------------- legacy CSR layout ----------------
    int*   degL     = (int*)wsp;
    float* gsumL    = (float*)(degL + N_NODES);
    float* gsum2L   = gsumL + NUM_GRAPHS * 64;
    float* gcntL    = gsum2L + NUM_GRAPHS * 64;
    size_t zeroL    = ((size_t)N_NODES + 2 * NUM_GRAPHS * 64 + 64) * 4;
    int*   offsetsL = (int*)(gcntL + 64);
    int*   blocksum = offsetsL + N_NODES + 1;
    int*   blockoff = blocksum + 64;
    int*   cursorL  = blockoff + 64;
    size_t csrL_off = (((size_t)((char*)(cursorL + N_NODES) - wsp)) + 15) & ~(size_t)15;
    int2*  csrL     = (int2*)(wsp + csrL_off);
    float* aggL     = (float*)(csrL + N_EDGES);
    float* AgL      = aggL + (size_t)N_NODES * 64;
    float* BgL      = AgL + NUM_GRAPHS * 64;
    size_t reqL     = (size_t)((char*)(BgL + NUM_GRAPHS * 64) - wsp);

    float *agg, *gsum, *gsum2, *gcnt, *Ag, *Bg;

    if (ws_size >= reqN) {
        hipMemsetAsync(d_ws, 0, zeroN, stream);
        countA_kernel<<<NBLK_A, A_THREADS, 0, stream>>>(dst_idx, bucket_cnt);
        scanA_kernel<<<1, 256, 0, stream>>>(bucket_cnt, bucket_base, bucket_cur, offsetsN);
        binA_kernel<<<NBLK_A, A_THREADS, 0, stream>>>(src_idx, dst_idx, ea, bucket_cur, binned);
        binB_kernel<<<NBUCKETS, 256, 0, stream>>>(binned, bucket_base, offsetsN, csrN);
        gather_kernel<<<(N_NODES + 3) / 4, 256, 0, stream>>>(x, offsetsN, csrN, aggN);
        agg = aggN; gsum = gsumN; gsum2 = gsum2N; gcnt = gcntN; Ag = AgN; Bg = BgN;
    } else if (ws_size >= reqL) {
        hipMemsetAsync(d_ws, 0, zeroL, stream);
        hist_kernel<<<(N_EDGES + 255) / 256, 256, 0, stream>>>(dst_idx, degL);
        scan1_kernel<<<NSCAN, SCAN_T, 0, stream>>>(degL, offsetsL, blocksum);
        scan2_kernel<<<1, 64, 0, stream>>>(blocksum, blockoff);
        scan3_kernel<<<(N_NODES + 255) / 256, 256, 0, stream>>>(offsetsL, blockoff, cursorL);
        fill_kernel<<<(N_EDGES + 255) / 256, 256, 0, stream>>>(src_idx, dst_idx, ea, cursorL, csrL);
        gather_kernel<<<(N_NODES + 3) / 4, 256, 0, stream>>>(x, offsetsL, csrL, aggL);
        agg = aggL; gsum = gsumL; gsum2 = gsum2L; gcnt = gcntL; Ag = AgL; Bg = BgL;
    } else {
        agg   = (float*)(gcntL + 64);
        Ag    = agg + (size_t)N_NODES * 64;
        Bg    = Ag + NUM_GRAPHS * 64;
        gsum = gsumL; gsum2 = gsum2L; gcnt = gcntL;
        size_t zb = zeroL + (size_t)N_NODES * 64 * 4;
        hipMemsetAsync(d_ws, 0, zb, stream);
        long long total = (long long)N_EDGES * 16;
        scatter_kernel<<<(int)((total + 255) / 256), 256, 0, stream>>>(
            x, src_idx, dst_idx, ea, agg);
    }

    dense_mfma_kernel<<<(N_NODES + DB - 1) / DB, 256, 0, stream>>>(
        agg, x, W_rel, b_rel, W_root);
    {
        int waves = (N_NODES + NPW - 1) / NPW;
        stats_kernel<<<(waves + 3) / 4, 256, 0, stream>>>(agg, batch, gsum, gsum2, gcnt);
    }
    finalize_kernel<<<(NUM_GRAPHS * 64 + 255) / 256, 256, 0, stream>>>(
        gsum, gsum2, gcnt, gn_w, gn_b, gn_ms, Ag, Bg);
    {
        long long total = (long long)N_NODES * 16;
        apply_kernel<<<(int)((total + 255) / 256), 256, 0, stream>>>(
            agg, batch, Ag, Bg, (float*)d_out);
    }
}

// Round 5
// 188.825 us; speedup vs baseline: 7.7581x; 1.0410x over previous
//
#include <hip/hip_runtime.h>

#define N_NODES 100000
#define N_EDGES 1600000
#define D 64
#define NUM_GRAPHS 64
#define EPS 1e-5f

// ---- bucketed CSR build params ----
#define BSHIFT 9
#define NPB 512
#define NBUCKETS ((N_NODES + NPB - 1) / NPB)      // 196
#define A_THREADS 1024
#define A_EPT 8
#define A_CHUNK (A_THREADS * A_EPT)               // 8192
#define NBLK_A ((N_EDGES + A_CHUNK - 1) / A_CHUNK) // 196

// ---- legacy scan params (fallback path) ----
#define SCAN_T 256
#define SCAN_E 8
#define SCAN_CHUNK (SCAN_T * SCAN_E)
#define NSCAN ((N_NODES + SCAN_CHUNK - 1) / SCAN_CHUNK)

typedef float f32x4 __attribute__((ext_vector_type(4)));
typedef short bf16x8 __attribute__((ext_vector_type(8)));

// ===========================================================================
// NEW PATH kernel 0: cast x (f32) -> xh (bf16, RNE) — 8 elems/thread
// ===========================================================================
__global__ __launch_bounds__(256) void xcast_kernel(
    const float* __restrict__ x, ushort* __restrict__ xh)
{
    int i = blockIdx.x * blockDim.x + threadIdx.x;
    if (i >= N_NODES * 64 / 8) return;
    const float4* src = reinterpret_cast<const float4*>(x) + (size_t)i * 2;
    float4 v0 = src[0], v1 = src[1];
    float vf[8] = {v0.x, v0.y, v0.z, v0.w, v1.x, v1.y, v1.z, v1.w};
    union { ushort us[8]; uint4 u4; } o;
    #pragma unroll
    for (int j = 0; j < 8; ++j) {
        unsigned int bits = __float_as_uint(vf[j]);
        o.us[j] = (ushort)((bits + 0x7FFFu + ((bits >> 16) & 1u)) >> 16);
    }
    reinterpret_cast<uint4*>(xh)[i] = o.u4;
}

// ===========================================================================
// NEW PATH kernel 1: per-bucket edge counts
// ===========================================================================
__global__ __launch_bounds__(A_THREADS) void countA_kernel(
    const int* __restrict__ dst_idx, int* __restrict__ bucket_cnt)
{
    __shared__ int hist[NBUCKETS];
    int tid = threadIdx.x;
    if (tid < NBUCKETS) hist[tid] = 0;
    __syncthreads();
    int base = blockIdx.x * A_CHUNK;
    #pragma unroll
    for (int i = 0; i < A_EPT; ++i) {
        int e = base + i * A_THREADS + tid;
        if (e < N_EDGES) atomicAdd(&hist[dst_idx[e] >> BSHIFT], 1);
    }
    __syncthreads();
    if (tid < NBUCKETS && hist[tid] > 0) atomicAdd(&bucket_cnt[tid], hist[tid]);
}

// ===========================================================================
// NEW PATH kernel 2: scan 196 bucket counts -> base + cursor
// ===========================================================================
__global__ __launch_bounds__(256) void scanA_kernel(
    const int* __restrict__ bucket_cnt, int* __restrict__ bucket_base,
    int* __restrict__ bucket_cursor, int* __restrict__ offsets)
{
    __shared__ int p[256];
    int tid = threadIdx.x;
    int c = (tid < NBUCKETS) ? bucket_cnt[tid] : 0;
    p[tid] = c;
    __syncthreads();
    for (int off = 1; off < 256; off <<= 1) {
        int v = p[tid];
        int a = (tid >= off) ? p[tid - off] : 0;
        __syncthreads();
        p[tid] = v + a;
        __syncthreads();
    }
    int ex = (tid == 0) ? 0 : p[tid - 1];
    if (tid < NBUCKETS) {
        bucket_base[tid] = ex;
        bucket_cursor[tid] = ex;
    }
    if (tid == 0) {
        bucket_base[NBUCKETS] = N_EDGES;
        offsets[N_NODES] = N_EDGES;
    }
}

// ===========================================================================
// NEW PATH kernel 3: bin edges by bucket
// packed entry: .x = src | (dst&511)<<17 ; .y = weight bits
// ===========================================================================
__global__ __launch_bounds__(A_THREADS) void binA_kernel(
    const int* __restrict__ src_idx, const int* __restrict__ dst_idx,
    const float* __restrict__ ea, int* __restrict__ bucket_cursor,
    int2* __restrict__ binned)
{
    __shared__ int hist[NBUCKETS];
    __shared__ int lbase[NBUCKETS];
    int tid = threadIdx.x;
    if (tid < NBUCKETS) hist[tid] = 0;
    __syncthreads();

    int base = blockIdx.x * A_CHUNK;
    int srcv[A_EPT], dstv[A_EPT];
    float wv[A_EPT];
    #pragma unroll
    for (int i = 0; i < A_EPT; ++i) {
        int e = base + i * A_THREADS + tid;
        if (e < N_EDGES) {
            srcv[i] = src_idx[e];
            dstv[i] = dst_idx[e];
            wv[i]   = ea[e];
            atomicAdd(&hist[dstv[i] >> BSHIFT], 1);
        } else {
            dstv[i] = -1; srcv[i] = 0; wv[i] = 0.f;
        }
    }
    __syncthreads();
    if (tid < NBUCKETS) lbase[tid] = atomicAdd(&bucket_cursor[tid], hist[tid]);
    __syncthreads();
    if (tid < NBUCKETS) hist[tid] = 0;
    __syncthreads();
    #pragma unroll
    for (int i = 0; i < A_EPT; ++i) {
        if (dstv[i] >= 0) {
            int b = dstv[i] >> BSHIFT;
            int r = atomicAdd(&hist[b], 1);
            binned[lbase[b] + r] =
                make_int2(srcv[i] | ((dstv[i] & (NPB - 1)) << 17),
                          __float_as_int(wv[i]));
        }
    }
}

// ===========================================================================
// NEW PATH kernel 4: per-bucket local counting sort -> offsets[] + csr[]
// ===========================================================================
__global__ __launch_bounds__(256) void binB_kernel(
    const int2* __restrict__ binned, const int* __restrict__ bucket_base,
    int* __restrict__ offsets, int2* __restrict__ csr)
{
    __shared__ int dcnt[NPB];
    __shared__ int doff[NPB];
    __shared__ int psum[256];
    int tid = threadIdx.x;
    int b = blockIdx.x;
    int beg = bucket_base[b];
    int end = bucket_base[b + 1];

    for (int i = tid; i < NPB; i += 256) dcnt[i] = 0;
    __syncthreads();
    for (int j = beg + tid; j < end; j += 256) {
        int px = binned[j].x;
        atomicAdd(&dcnt[px >> 17], 1);
    }
    __syncthreads();
    int e0 = dcnt[2 * tid], e1 = dcnt[2 * tid + 1];
    psum[tid] = e0 + e1;
    __syncthreads();
    for (int off = 1; off < 256; off <<= 1) {
        int v = psum[tid];
        int a = (tid >= off) ? psum[tid - off] : 0;
        __syncthreads();
        psum[tid] = v + a;
        __syncthreads();
    }
    int ex = (tid == 0) ? 0 : psum[tid - 1];
    doff[2 * tid] = ex;
    doff[2 * tid + 1] = ex + e0;
    __syncthreads();
    for (int i = tid; i < NPB; i += 256) {
        int node = (b << BSHIFT) + i;
        if (node < N_NODES) offsets[node] = beg + doff[i];
        dcnt[i] = doff[i];
    }
    __syncthreads();
    for (int j = beg + tid; j < end; j += 256) {
        int2 v = binned[j];
        int dlo = v.x >> 17;
        int r = atomicAdd(&dcnt[dlo], 1);
        csr[beg + r] = make_int2(v.x & 0x1FFFF, v.y);
    }
}

// ===========================================================================
// Gather-aggregate (bf16 x table): one wave per node, lane = dim
// ===========================================================================
__global__ __launch_bounds__(256) void gatherh_kernel(
    const ushort* __restrict__ xh, const int* __restrict__ offsets,
    const int2* __restrict__ csr, float* __restrict__ agg)
{
    int wid = (int)((blockIdx.x * blockDim.x + threadIdx.x) >> 6);
    if (wid >= N_NODES) return;
    int lane = threadIdx.x & 63;
    int beg = __builtin_amdgcn_readfirstlane(offsets[wid]);
    int end = __builtin_amdgcn_readfirstlane(offsets[wid + 1]);
    float acc0 = 0.f, acc1 = 0.f, acc2 = 0.f, acc3 = 0.f;
    int j = beg;
    for (; j + 3 < end; j += 4) {
        int2 a = csr[j];
        int2 b = csr[j + 1];
        int2 c = csr[j + 2];
        int2 d = csr[j + 3];
        float xa = __uint_as_float((unsigned int)xh[(size_t)a.x * 64 + lane] << 16);
        float xb = __uint_as_float((unsigned int)xh[(size_t)b.x * 64 + lane] << 16);
        float xc = __uint_as_float((unsigned int)xh[(size_t)c.x * 64 + lane] << 16);
        float xd = __uint_as_float((unsigned int)xh[(size_t)d.x * 64 + lane] << 16);
        acc0 = fmaf(__int_as_float(a.y), xa, acc0);
        acc1 = fmaf(__int_as_float(b.y), xb, acc1);
        acc2 = fmaf(__int_as_float(c.y), xc, acc2);
        acc3 = fmaf(__int_as_float(d.y), xd, acc3);
    }
    for (; j < end; ++j) {
        int2 a = csr[j];
        float xa = __uint_as_float((unsigned int)xh[(size_t)a.x * 64 + lane] << 16);
        acc0 = fmaf(__int_as_float(a.y), xa, acc0);
    }
    agg[(size_t)wid * 64 + lane] = (acc0 + acc1) + (acc2 + acc3);
}

// f32 gather fallback (ws tier 2)
__global__ __launch_bounds__(256) void gather_kernel(
    const float* __restrict__ x, const int* __restrict__ offsets,
    const int2* __restrict__ csr, float* __restrict__ agg)
{
    int wid = (int)((blockIdx.x * blockDim.x + threadIdx.x) >> 6);
    if (wid >= N_NODES) return;
    int lane = threadIdx.x & 63;
    int beg = __builtin_amdgcn_readfirstlane(offsets[wid]);
    int end = __builtin_amdgcn_readfirstlane(offsets[wid + 1]);
    float acc0 = 0.f, acc1 = 0.f;
    int j = beg;
    for (; j + 1 < end; j += 2) {
        int2 a = csr[j];
        int2 b = csr[j + 1];
        acc0 = fmaf(__int_as_float(a.y), x[(size_t)a.x * 64 + lane], acc0);
        acc1 = fmaf(__int_as_float(b.y), x[(size_t)b.x * 64 + lane], acc1);
    }
    if (j < end) {
        int2 a = csr[j];
        acc0 = fmaf(__int_as_float(a.y), x[(size_t)a.x * 64 + lane], acc0);
    }
    agg[(size_t)wid * 64 + lane] = acc0 + acc1;
}

// ===========================================================================
// LEGACY PATH (fallback tier 3)
// ===========================================================================
__global__ __launch_bounds__(256) void hist_kernel(
    const int* __restrict__ dst_idx, int* __restrict__ deg)
{
    int e = blockIdx.x * blockDim.x + threadIdx.x;
    if (e >= N_EDGES) return;
    atomicAdd(&deg[dst_idx[e]], 1);
}

__global__ __launch_bounds__(SCAN_T) void scan1_kernel(
    const int* __restrict__ deg, int* __restrict__ offsets,
    int* __restrict__ blocksum)
{
    __shared__ int lds[SCAN_T];
    int b = blockIdx.x, t = threadIdx.x;
    int base = b * SCAN_CHUNK + t * SCAN_E;
    int v[SCAN_E];
    int s = 0;
    #pragma unroll
    for (int i = 0; i < SCAN_E; ++i) {
        v[i] = (base + i < N_NODES) ? deg[base + i] : 0;
        s += v[i];
    }
    lds[t] = s;
    __syncthreads();
    for (int off = 1; off < SCAN_T; off <<= 1) {
        int val = lds[t];
        int add = (t >= off) ? lds[t - off] : 0;
        __syncthreads();
        lds[t] = val + add;
        __syncthreads();
    }
    if (t == SCAN_T - 1) blocksum[b] = lds[SCAN_T - 1];
    int run = (t == 0) ? 0 : lds[t - 1];
    #pragma unroll
    for (int i = 0; i < SCAN_E; ++i) {
        if (base + i < N_NODES) offsets[base + i] = run;
        run += v[i];
    }
}

__global__ __launch_bounds__(64) void scan2_kernel(
    const int* __restrict__ blocksum, int* __restrict__ blockoff)
{
    __shared__ int lds[64];
    int t = threadIdx.x;
    lds[t] = (t < NSCAN) ? blocksum[t] : 0;
    __syncthreads();
    for (int off = 1; off < 64; off <<= 1) {
        int val = lds[t];
        int add = (t >= off) ? lds[t - off] : 0;
        __syncthreads();
        lds[t] = val + add;
        __syncthreads();
    }
    if (t < NSCAN) blockoff[t] = (t == 0) ? 0 : lds[t - 1];
}

__global__ __launch_bounds__(256) void scan3_kernel(
    int* __restrict__ offsets, const int* __restrict__ blockoff,
    int* __restrict__ cursor)
{
    int i = blockIdx.x * blockDim.x + threadIdx.x;
    if (i < N_NODES) {
        int v = offsets[i] + blockoff[i / SCAN_CHUNK];
        offsets[i] = v;
        cursor[i] = v;
    }
    if (i == 0) offsets[N_NODES] = N_EDGES;
}

__global__ __launch_bounds__(256) void fill_kernel(
    const int* __restrict__ src_idx, const int* __restrict__ dst_idx,
    const float* __restrict__ ea, int* __restrict__ cursor,
    int2* __restrict__ csr)
{
    int e = blockIdx.x * blockDim.x + threadIdx.x;
    if (e >= N_EDGES) return;
    int s = src_idx[e];
    int d = dst_idx[e];
    float w = ea[e];
    int pos = atomicAdd(&cursor[d], 1);
    csr[pos] = make_int2(s, __float_as_int(w));
}

// ===========================================================================
// LAST-RESORT fallback: atomic scatter
// ===========================================================================
__global__ __launch_bounds__(256) void scatter_kernel(
    const float* __restrict__ x,
    const int* __restrict__ src_idx,
    const int* __restrict__ dst_idx,
    const float* __restrict__ ea,
    float* __restrict__ agg)
{
    long long gid = (long long)blockIdx.x * blockDim.x + threadIdx.x;
    if (gid >= (long long)N_EDGES * 16) return;
    int e = (int)(gid >> 4);
    int q = (int)(gid & 15);
    int s = src_idx[e];
    int d = dst_idx[e];
    float w = ea[e];
    float4 v = reinterpret_cast<const float4*>(x)[(size_t)s * 16 + q];
    float* out = agg + (size_t)d * 64 + q * 4;
    atomicAdd(out + 0, w * v.x);
    atomicAdd(out + 1, w * v.y);
    atomicAdd(out + 2, w * v.z);
    atomicAdd(out + 3, w * v.w);
}

// ===========================================================================
// Kernel B (MFMA): h = relu([agg|x] @ [W_rel^T; W_root^T] + b), in-place.
// ===========================================================================
#define DB 128
__global__ __launch_bounds__(256) void dense_mfma_kernel(
    float* __restrict__ aggh,
    const float* __restrict__ x,
    const float* __restrict__ W_rel,
    const float* __restrict__ b_rel,
    const float* __restrict__ W_root)
{
    __shared__ unsigned int Bf[2][4][4][64][4];   // [hi/lo][kt][dt][lane][4xu32] = 32 KB
    int tid = threadIdx.x;

    #pragma unroll
    for (int g = 0; g < 8; ++g) {
        int q = tid * 8 + g;
        int i4   = (q & 1) * 4;
        int lane = (q >> 1) & 63;
        int dt   = (q >> 7) & 3;
        int kt   = (q >> 9) & 3;
        int d = dt * 16 + (lane & 15);
        int k = kt * 32 + (lane >> 4) * 8 + i4;
        const float* Wsrc = (k < 64) ? (W_rel + d * 64 + k)
                                     : (W_root + d * 64 + (k - 64));
        float4 w = *reinterpret_cast<const float4*>(Wsrc);
        float wf[4] = {w.x, w.y, w.z, w.w};
        unsigned int hi[4], lo[4];
        #pragma unroll
        for (int j = 0; j < 4; ++j) {
            unsigned int bits = __float_as_uint(wf[j]);
            hi[j] = bits >> 16;
            float resid = wf[j] - __uint_as_float(bits & 0xFFFF0000u);
            lo[j] = __float_as_uint(resid) >> 16;
        }
        int u = i4 >> 1;
        Bf[0][kt][dt][lane][u]     = hi[0] | (hi[1] << 16);
        Bf[0][kt][dt][lane][u + 1] = hi[2] | (hi[3] << 16);
        Bf[1][kt][dt][lane][u]     = lo[0] | (lo[1] << 16);
        Bf[1][kt][dt][lane][u + 1] = lo[2] | (lo[3] << 16);
    }
    __syncthreads();

    int wid = tid >> 6, lane = tid & 63;
    int nbase = blockIdx.x * DB + wid * 32;
    int r = lane & 15;
    int k0 = (lane >> 4) * 8;

    f32x4 acc[2][4];
    #pragma unroll
    for (int nt = 0; nt < 2; ++nt)
        #pragma unroll
        for (int dt = 0; dt < 4; ++dt)
            acc[nt][dt] = (f32x4){0.f, 0.f, 0.f, 0.f};

    #pragma unroll 1
    for (int kt = 0; kt < 4; ++kt) {
        bf16x8 bh[4], bl[4];
        #pragma unroll
        for (int dt = 0; dt < 4; ++dt) {
            bh[dt] = *reinterpret_cast<const bf16x8*>(&Bf[0][kt][dt][lane][0]);
            bl[dt] = *reinterpret_cast<const bf16x8*>(&Bf[1][kt][dt][lane][0]);
        }
        int kk = kt * 32 + k0;
        #pragma unroll
        for (int nt = 0; nt < 2; ++nt) {
            int node = nbase + nt * 16 + r;
            float av[8];
            if (node < N_NODES) {
                const float* srcrow = (kk < 64)
                    ? (aggh + (size_t)node * 64 + kk)
                    : (x + (size_t)node * 64 + (kk - 64));
                float4 v0 = reinterpret_cast<const float4*>(srcrow)[0];
                float4 v1 = reinterpret_cast<const float4*>(srcrow)[1];
                av[0] = v0.x; av[1] = v0.y; av[2] = v0.z; av[3] = v0.w;
                av[4] = v1.x; av[5] = v1.y; av[6] = v1.z; av[7] = v1.w;
            } else {
                #pragma unroll
                for (int i = 0; i < 8; ++i) av[i] = 0.f;
            }
            bf16x8 ah, al;
            #pragma unroll
            for (int i = 0; i < 8; ++i) {
                unsigned int bits = __float_as_uint(av[i]);
                ah[i] = (short)(bits >> 16);
                float resid = av[i] - __uint_as_float(bits & 0xFFFF0000u);
                al[i] = (short)(__float_as_uint(resid) >> 16);
            }
            #pragma unroll
            for (int dt = 0; dt < 4; ++dt) {
                acc[nt][dt] = __builtin_amdgcn_mfma_f32_16x16x32_bf16(ah, bh[dt], acc[nt][dt], 0, 0, 0);
                acc[nt][dt] = __builtin_amdgcn_mfma_f32_16x16x32_bf16(al, bh[dt], acc[nt][dt], 0, 0, 0);
                acc[nt][dt] = __builtin_amdgcn_mfma_f32_16x16x32_bf16(ah, bl[dt], acc[nt][dt], 0, 0, 0);
            }
        }
    }

    int rowg = (lane >> 4) * 4;
    #pragma unroll
    for (int dt = 0; dt < 4; ++dt) {
        int d = dt * 16 + r;
        float bias = b_rel[d];
        #pragma unroll
        for (int nt = 0; nt < 2; ++nt) {
            #pragma unroll
            for (int reg = 0; reg < 4; ++reg) {
                int node = nbase + nt * 16 + rowg + reg;
                if (node < N_NODES) {
                    float v = fmaxf(acc[nt][dt][reg] + bias, 0.f);
                    aggh[(size_t)node * 64 + d] = v;
                }
            }
        }
    }
}

// ===========================================================================
// Kernel C1: per-(graph, dim) sum(h), sum(h^2), per-graph count
// ===========================================================================
#define NPW 32
__global__ __launch_bounds__(256) void stats_kernel(
    const float* __restrict__ h,
    const int* __restrict__ batch,
    float* __restrict__ gsum,
    float* __restrict__ gsum2,
    float* __restrict__ gcnt)
{
    int wave = (int)((blockIdx.x * blockDim.x + threadIdx.x) >> 6);
    int lane = threadIdx.x & 63;
    int base = wave * NPW;
    if (base >= N_NODES) return;
    int end = min(base + NPW, N_NODES);

    int gcur = batch[base];
    float s = 0.f, s2 = 0.f, cnt = 0.f;
    for (int n = base; n < end; ++n) {
        int g = batch[n];
        if (g != gcur) {
            atomicAdd(&gsum[gcur * 64 + lane], s);
            atomicAdd(&gsum2[gcur * 64 + lane], s2);
            if (lane == 0) atomicAdd(&gcnt[gcur], cnt);
            s = 0.f; s2 = 0.f; cnt = 0.f;
            gcur = g;
        }
        float v = h[(size_t)n * 64 + lane];
        s += v;
        s2 = fmaf(v, v, s2);
        cnt += 1.f;
    }
    atomicAdd(&gsum[gcur * 64 + lane], s);
    atomicAdd(&gsum2[gcur * 64 + lane], s2);
    if (lane == 0) atomicAdd(&gcnt[gcur], cnt);
}

// ===========================================================================
// Kernel C2: fold stats into per-(g,d) affine A,B
// ===========================================================================
__global__ __launch_bounds__(256) void finalize_kernel(
    const float* __restrict__ gsum,
    const float* __restrict__ gsum2,
    const float* __restrict__ gcnt,
    const float* __restrict__ gn_w,
    const float* __restrict__ gn_b,
    const float* __restrict__ gn_ms,
    float* __restrict__ Ag,
    float* __restrict__ Bg)
{
    int i = blockIdx.x * blockDim.x + threadIdx.x;
    if (i >= NUM_GRAPHS * 64) return;
    int g = i >> 6, d = i & 63;
    float c = fmaxf(gcnt[g], 1.f);
    float m = gsum[i] / c;
    float q = gsum2[i] / c;
    float s = gn_ms[d];
    float var = q - (2.f * s - s * s) * m * m;
    float inv = rsqrtf(fmaxf(var, 0.f) + EPS);
    float A = gn_w[d] * inv;
    Ag[i] = A;
    Bg[i] = gn_b[d] - A * s * m;
}

// ===========================================================================
// Kernel C3: out[n][d] = A[g][d] * h[n][d] + B[g][d]
// ===========================================================================
__global__ __launch_bounds__(256) void apply_kernel(
    const float* __restrict__ h,
    const int* __restrict__ batch,
    const float* __restrict__ Ag,
    const float* __restrict__ Bg,
    float* __restrict__ out)
{
    long long gid = (long long)blockIdx.x * blockDim.x + threadIdx.x;
    if (gid >= (long long)N_NODES * 16) return;
    int n = (int)(gid >> 4);
    int q = (int)(gid & 15);
    int g = batch[n];
    float4 hv = reinterpret_cast<const float4*>(h)[gid];
    float4 A = reinterpret_cast<const float4*>(Ag)[g * 16 + q];
    float4 B = reinterpret_cast<const float4*>(Bg)[g * 16 + q];
    float4 o;
    o.x = fmaf(A.x, hv.x, B.x);
    o.y = fmaf(A.y, hv.y, B.y);
    o.z = fmaf(A.z, hv.z, B.z);
    o.w = fmaf(A.w, hv.w, B.w);
    reinterpret_cast<float4*>(out)[gid] = o;
}

// ===========================================================================
extern "C" void kernel_launch(void* const* d_in, const int* in_sizes, int n_in,
                              void* d_out, int out_size, void* d_ws, size_t ws_size,
                              hipStream_t stream)
{
    const float* x      = (const float*)d_in[0];
    const int*   ei     = (const int*)d_in[1];
    const float* ea     = (const float*)d_in[2];
    const int*   batch  = (const int*)d_in[3];
    const float* W_rel  = (const float*)d_in[4];
    const float* b_rel  = (const float*)d_in[5];
    const float* W_root = (const float*)d_in[6];
    const float* gn_w   = (const float*)d_in[7];
    const float* gn_b   = (const float*)d_in[8];
    const float* gn_ms  = (const float*)d_in[9];
    const int* src_idx = ei;
    const int* dst_idx = ei + N_EDGES;

    char* wsp = (char*)d_ws;

    // ---------------- NEW path layout ----------------
    int*   bucket_cnt  = (int*)wsp;
    float* gsumN       = (float*)(bucket_cnt + 256);
    float* gsum2N      = gsumN + NUM_GRAPHS * 64;
    float* gcntN       = gsum2N + NUM_GRAPHS * 64;
    size_t zeroN       = ((size_t)256 + 2 * NUM_GRAPHS * 64 + 64) * 4;
    int*   bucket_base = (int*)(gcntN + 64);
    int*   bucket_cur  = bucket_base + 256;
    int*   offsetsN    = bucket_cur + 256;
    size_t binned_off  = (((size_t)((char*)(offsetsN + N_NODES + 1) - wsp)) + 15) & ~(size_t)15;
    int2*  binned      = (int2*)(wsp + binned_off);
    int2*  csrN        = binned + N_EDGES;
    float* aggN        = (float*)(csrN + N_EDGES);
    float* AgN         = aggN + (size_t)N_NODES * 64;
    float* BgN         = AgN + NUM_GRAPHS * 64;
    size_t reqN        = (size_t)((char*)(BgN + NUM_GRAPHS * 64) - wsp);
    ushort* xh         = (ushort*)(BgN + NUM_GRAPHS * 64);      // N*64 bf16
    size_t reqN2       = (size_t)((char*)(xh + (size_t)N_NODES * 64) - wsp);

    // ---------------- legacy CSR layout ----------------
    int*   degL     = (int*)wsp;
    float* gsumL    = (float*)(degL + N_NODES);
    float* gsum2L   = gsumL + NUM_GRAPHS * 64;
    float* gcntL    = gsum2L + NUM_GRAPHS * 64;
    size_t zeroL    = ((size_t)N_NODES + 2 * NUM_GRAPHS * 64 + 64) * 4;
    int*   offsetsL = (int*)(gcntL + 64);
    int*   blocksum = offsetsL + N_NODES + 1;
    int*   blockoff = blocksum + 64;
    int*   cursorL  = blockoff + 64;
    size_t csrL_off = (((size_t)((char*)(cursorL + N_NODES) - wsp)) + 15) & ~(size_t)15;
    int2*  csrL     = (int2*)(wsp + csrL_off);
    float* aggL     = (float*)(csrL + N_EDGES);
    float* AgL      = aggL + (size_t)N_NODES * 64;
    float* BgL      = AgL + NUM_GRAPHS * 64;
    size_t reqL     = (size_t)((char*)(BgL + NUM_GRAPHS * 64) - wsp);

    float *agg, *gsum, *gsum2, *gcnt, *Ag, *Bg;

    if (ws_size >= reqN) {
        hipMemsetAsync(d_ws, 0, zeroN, stream);
        countA_kernel<<<NBLK_A, A_THREADS, 0, stream>>>(dst_idx, bucket_cnt);
        scanA_kernel<<<1, 256, 0, stream>>>(bucket_cnt, bucket_base, bucket_cur, offsetsN);
        binA_kernel<<<NBLK_A, A_THREADS, 0, stream>>>(src_idx, dst_idx, ea, bucket_cur, binned);
        binB_kernel<<<NBUCKETS, 256, 0, stream>>>(binned, bucket_base, offsetsN, csrN);
        if (ws_size >= reqN2) {
            xcast_kernel<<<(N_NODES * 64 / 8 + 255) / 256, 256, 0, stream>>>(x, xh);
            gatherh_kernel<<<(N_NODES + 3) / 4, 256, 0, stream>>>(xh, offsetsN, csrN, aggN);
        } else {
            gather_kernel<<<(N_NODES + 3) / 4, 256, 0, stream>>>(x, offsetsN, csrN, aggN);
        }
        agg = aggN; gsum = gsumN; gsum2 = gsum2N; gcnt = gcntN; Ag = AgN; Bg = BgN;
    } else if (ws_size >= reqL) {
        hipMemsetAsync(d_ws, 0, zeroL, stream);
        hist_kernel<<<(N_EDGES + 255) / 256, 256, 0, stream>>>(dst_idx, degL);
        scan1_kernel<<<NSCAN, SCAN_T, 0, stream>>>(degL, offsetsL, blocksum);
        scan2_kernel<<<1, 64, 0, stream>>>(blocksum, blockoff);
        scan3_kernel<<<(N_NODES + 255) / 256, 256, 0, stream>>>(offsetsL, blockoff, cursorL);
        fill_kernel<<<(N_EDGES + 255) / 256, 256, 0, stream>>>(src_idx, dst_idx, ea, cursorL, csrL);
        gather_kernel<<<(N_NODES + 3) / 4, 256, 0, stream>>>(x, offsetsL, csrL, aggL);
        agg = aggL; gsum = gsumL; gsum2 = gsum2L; gcnt = gcntL; Ag = AgL; Bg = BgL;
    } else {
        agg   = (float*)(gcntL + 64);
        Ag    = agg + (size_t)N_NODES * 64;
        Bg    = Ag + NUM_GRAPHS * 64;
        gsum = gsumL; gsum2 = gsum2L; gcnt = gcntL;
        size_t zb = zeroL + (size_t)N_NODES * 64 * 4;
        hipMemsetAsync(d_ws, 0, zb, stream);
        long long total = (long long)N_EDGES * 16;
        scatter_kernel<<<(int)((total + 255) / 256), 256, 0, stream>>>(
            x, src_idx, dst_idx, ea, agg);
    }

    dense_mfma_kernel<<<(N_NODES + DB - 1) / DB, 256, 0, stream>>>(
        agg, x, W_rel, b_rel, W_root);
    {
        int waves = (N_NODES + NPW - 1) / NPW;
        stats_kernel<<<(waves + 3) / 4, 256, 0, stream>>>(agg, batch, gsum, gsum2, gcnt);
    }
    finalize_kernel<<<(NUM_GRAPHS * 64 + 255) / 256, 256, 0, stream>>>(
        gsum, gsum2, gcnt, gn_w, gn_b, gn_ms, Ag, Bg);
    {
        long long total = (long long)N_NODES * 16;
        apply_kernel<<<(int)((total + 255) / 256), 256, 0, stream>>>(
            agg, batch, Ag, Bg, (float*)d_out);
    }
}